// Round 13
// baseline (1811.032 us; speedup 1.0000x reference)
//
#include <hip/hip_runtime.h>

typedef signed char I8;
typedef __attribute__((ext_vector_type(4))) int i32x4;
typedef __attribute__((ext_vector_type(4))) float f32x4;

#define B_   8
#define T_   2048
#define D_   1024
#define QD_  256
#define L_   4
#define M_   (B_ * T_)      // 16384
#define NCLS_ 1000
#define DD_  (D_ * D_)

// ---------- helpers ----------
__device__ __forceinline__ float fixf(float v) {
  unsigned u = __float_as_uint(v);
  return ((u & 0x7F800000u) == 0x7F800000u) ? 0.f : v;
}
__device__ __forceinline__ void glds16(const void* g, void* l) {
  __builtin_amdgcn_global_load_lds((const __attribute__((address_space(1))) void*)g,
                                   (__attribute__((address_space(3))) void*)l, 16, 0, 0);
}
__device__ __forceinline__ int clampi(int q) { return q < -128 ? -128 : (q > 127 ? 127 : q); }
// quantize v (|v| <= 127/inv) to 16-bit fixed point: v ~= (qh + ql/256)/inv
__device__ __forceinline__ void quant2(float v, float inv, int& qh, int& ql) {
  const float t = v * inv;
  int h = clampi((int)rintf(t));
  const float r = t - (float)h;
  int l = clampi((int)rintf(r * 256.f));
  qh = h; ql = l;
}
// block=256 (4 waves): reduce two sums across block
__device__ __forceinline__ void breduce2(float& a, float& b, float* buf) {
#pragma unroll
  for (int off = 32; off > 0; off >>= 1) { a += __shfl_down(a, off); b += __shfl_down(b, off); }
  const int lane = threadIdx.x & 63, w = threadIdx.x >> 6;
  __syncthreads();
  if (lane == 0) { buf[w] = a; buf[4 + w] = b; }
  __syncthreads();
  a = buf[0] + buf[1] + buf[2] + buf[3];
  b = buf[4] + buf[5] + buf[6] + buf[7];
}
// block=256: max across block
__device__ __forceinline__ float bmaxall(float a, float* buf) {
#pragma unroll
  for (int off = 32; off > 0; off >>= 1) a = fmaxf(a, __shfl_down(a, off));
  const int lane = threadIdx.x & 63, w = threadIdx.x >> 6;
  __syncthreads();
  if (lane == 0) buf[w] = a;
  __syncthreads();
  return fmaxf(fmaxf(buf[0], buf[1]), fmaxf(buf[2], buf[3]));
}

// ---------- weight quant: f32 -> i8 hi/lo planes + per-row scale, Q+R+H fused ----------
// one block per (sec, n): W[n][k] row of 1024; sw[sec*D+n] = rowmax/127
__global__ __launch_bounds__(256) void wsplitq_k(const float* __restrict__ Wq,
                                                 const float* __restrict__ Wr,
                                                 const float* __restrict__ Wh,
                                                 I8* __restrict__ hi, I8* __restrict__ lo,
                                                 float* __restrict__ sw) {
  __shared__ float red[4];
  const int sec = blockIdx.x >> 10;
  const int n = blockIdx.x & 1023;
  const float* w = (sec == 0) ? Wq : (sec == 1) ? Wr : Wh;
  const int c = threadIdx.x * 4;
  const float4 v = *(const float4*)(w + (size_t)n * D_ + c);
  const float vv[4] = {v.x, v.y, v.z, v.w};
  float mx = fmaxf(fmaxf(fabsf(v.x), fabsf(v.y)), fmaxf(fabsf(v.z), fabsf(v.w)));
  mx = bmaxall(mx, red);
  const float s = fmaxf(mx, 1e-30f) * (1.f / 127.f);
  if (threadIdx.x == 0) sw[sec * D_ + n] = s;
  const float inv = 127.f / fmaxf(mx, 1e-30f);
  unsigned ph = 0, pl = 0;
#pragma unroll
  for (int j = 0; j < 4; j++) {
    int qh, ql;
    quant2(vv[j], inv, qh, ql);
    ph |= ((unsigned)(unsigned char)(I8)qh) << (8 * j);
    pl |= ((unsigned)(unsigned char)(I8)ql) << (8 * j);
  }
  const size_t o = (size_t)sec * DD_ + (size_t)n * D_ + c;
  *(unsigned*)(hi + o) = ph;
  *(unsigned*)(lo + o) = pl;
}

// ---------- embed: x = embed[tokens] + pos -> i8 hi/lo planes + per-row scale ----------
__global__ __launch_bounds__(256) void embedq_k(const int* __restrict__ tok,
                                                const float* __restrict__ emb,
                                                const float* __restrict__ pos,
                                                I8* __restrict__ xh, I8* __restrict__ xl,
                                                float* __restrict__ sx) {
  __shared__ float red[4];
  const int m = blockIdx.x;
  const int t = m & (T_ - 1);
  const int tk = tok[m];
  const int c = threadIdx.x * 4;
  const float* e = emb + (size_t)tk * D_ + c;
  const float* p = pos + (size_t)t * D_ + c;
  float v[4];
  float mx = 0.f;
#pragma unroll
  for (int i = 0; i < 4; i++) { v[i] = e[i] + p[i]; mx = fmaxf(mx, fabsf(v[i])); }
  mx = bmaxall(mx, red);
  const float s = fmaxf(mx, 1e-30f) * (1.f / 127.f);
  if (threadIdx.x == 0) sx[m] = s;
  const float inv = 127.f / fmaxf(mx, 1e-30f);
  unsigned ph = 0, pl = 0;
#pragma unroll
  for (int i = 0; i < 4; i++) {
    int qh, ql;
    quant2(v[i], inv, qh, ql);
    ph |= ((unsigned)(unsigned char)(I8)qh) << (8 * i);
    pl |= ((unsigned)(unsigned char)(I8)ql) << (8 * i);
  }
  const size_t o = (size_t)m * D_ + c;
  *(unsigned*)(xh + o) = ph;
  *(unsigned*)(xl + o) = pl;
}

// ---------- GEMM (i8 fixed-point): C = sx[m]*sw[n]*(hh + cross/256) + bias, Q+R+H fused ----
// 128x128 tile, BK=64 i8, 4 waves of 64x64, mfma_i32_16x16x64_i8.
// Double-buffered LDS + counted vmcnt: prefetch next tile, wait vmcnt(8) so only the
// previous tile's 8 loads drain; this iteration's 8 prefetch loads stay in flight.
// grid.x = 24: 0-7 -> Q (TR), 8-15 -> R (TR), 16-23 -> H (natural).
__global__ __launch_bounds__(256, 2) void gemm3q_k(const I8* __restrict__ Ahi,
                                                   const I8* __restrict__ Alo,
                                                   const I8* __restrict__ Whi,
                                                   const I8* __restrict__ Wlo,
                                                   const float* __restrict__ sx,
                                                   const float* __restrict__ sw,
                                                   const float* __restrict__ bq,
                                                   const float* __restrict__ br,
                                                   const float* __restrict__ bh,
                                                   float* __restrict__ outQ,
                                                   float* __restrict__ outR,
                                                   float* __restrict__ outH) {
  __shared__ __align__(16) I8 lds[65536];  // 2 buffers x 32KB: Ahi[0,8K) Alo[8K,16K) Bhi[16K,24K) Blo[24K,32K)
  char* sbase = (char*)lds;
  const int tid = threadIdx.x;
  const int lane = tid & 63;
  const int wave = tid >> 6;
  const int wr = wave >> 1, wc = wave & 1;
  const int sec = blockIdx.x >> 3;
  const int n0 = (blockIdx.x & 7) * 128;
  const int m0 = blockIdx.y * 128;
  const I8* Bhi = Whi + (size_t)sec * DD_;
  const I8* Blo = Wlo + (size_t)sec * DD_;
  const float* bias = (sec == 0) ? bq : (sec == 1) ? br : bh;
  float* out = (sec == 0) ? outQ : (sec == 1) ? outR : outH;
  const bool TR = sec < 2;

  i32x4 aHH[4][4], aX[4][4];
#pragma unroll
  for (int i = 0; i < 4; i++)
#pragma unroll
    for (int j = 0; j < 4; j++) { aHH[i][j] = (i32x4){0, 0, 0, 0}; aX[i][j] = (i32x4){0, 0, 0, 0}; }

  const int lrow = tid >> 2;            // 0..63
  const int lcolb = (tid & 3) * 16;     // bytes within 64B k-row
  const char* gah = (const char*)Ahi + (size_t)(m0 + lrow) * D_ + lcolb;
  const char* gal = (const char*)Alo + (size_t)(m0 + lrow) * D_ + lcolb;
  const char* gbh = (const char*)Bhi + (size_t)(n0 + lrow) * D_ + lcolb;
  const char* gbl = (const char*)Blo + (size_t)(n0 + lrow) * D_ + lcolb;

  const int koff = (lane >> 4) * 16;                 // byte k-offset of fragment
  const int mA = (wr * 64 + (lane & 15)) * 64;       // byte row base (A)
  const int nB = (wc * 64 + (lane & 15)) * 64;       // byte row base (B)

  // ---- prologue: stage K-tile 0 into buffer 0, drain fully ----
  {
    char* d = sbase + tid * 16;
    glds16(gah, d);
    glds16(gah + 64 * D_, d + 4096);
    glds16(gal, d + 8192);
    glds16(gal + 64 * D_, d + 12288);
    glds16(gbh, d + 16384);
    glds16(gbh + 64 * D_, d + 20480);
    glds16(gbl, d + 24576);
    glds16(gbl + 64 * D_, d + 28672);
    gah += 64; gal += 64; gbh += 64; gbl += 64;
  }
  asm volatile("s_waitcnt vmcnt(0)" ::: "memory");
  __builtin_amdgcn_s_barrier();

  int cur = 0;
  for (int kk = 0; kk < 1024; kk += 64) {
    // ---- issue next K-tile into the other buffer (no wait) ----
    if (kk < 1024 - 64) {
      char* d = sbase + (cur ^ 1) * 32768 + tid * 16;
      glds16(gah, d);
      glds16(gah + 64 * D_, d + 4096);
      glds16(gal, d + 8192);
      glds16(gal + 64 * D_, d + 12288);
      glds16(gbh, d + 16384);
      glds16(gbh + 64 * D_, d + 20480);
      glds16(gbl, d + 24576);
      glds16(gbl + 64 * D_, d + 28672);
      gah += 64; gal += 64; gbh += 64; gbl += 64;
      // drain only the OLDER 8 loads (previous tile -> buf cur); keep these 8 in flight
      asm volatile("s_waitcnt vmcnt(8)" ::: "memory");
    } else {
      asm volatile("s_waitcnt vmcnt(0)" ::: "memory");
    }
    __builtin_amdgcn_s_barrier();       // all waves: cur-tile data resident
    // ---- compute from current buffer ----
    const char* sb = sbase + cur * 32768;
    i32x4 ah[4], al[4], bh2[4], bl2[4];
#pragma unroll
    for (int i = 0; i < 4; i++) {
      const char* pa = sb + mA + i * 1024 + koff;
      ah[i] = *(const i32x4*)pa;
      al[i] = *(const i32x4*)(pa + 8192);
    }
#pragma unroll
    for (int j = 0; j < 4; j++) {
      const char* pb = sb + 16384 + nB + j * 1024 + koff;
      bh2[j] = *(const i32x4*)pb;
      bl2[j] = *(const i32x4*)(pb + 8192);
    }
#pragma unroll
    for (int i = 0; i < 4; i++)
#pragma unroll
      for (int j = 0; j < 4; j++) {
        aHH[i][j] = __builtin_amdgcn_mfma_i32_16x16x64_i8(ah[i], bh2[j], aHH[i][j], 0, 0, 0);
        aX[i][j]  = __builtin_amdgcn_mfma_i32_16x16x64_i8(ah[i], bl2[j], aX[i][j], 0, 0, 0);
        aX[i][j]  = __builtin_amdgcn_mfma_i32_16x16x64_i8(al[i], bh2[j], aX[i][j], 0, 0, 0);
      }
    __builtin_amdgcn_s_barrier();       // reads of buf cur done before next iter overwrites it
    cur ^= 1;
  }

#pragma unroll
  for (int j = 0; j < 4; j++) {
    const int n = n0 + wc * 64 + j * 16 + (lane & 15);
    const float swv = sw[sec * D_ + n];
    const float bv = bias[n];
#pragma unroll
    for (int i = 0; i < 4; i++) {
      const int mb = m0 + wr * 64 + i * 16 + ((lane >> 4) << 2);
#pragma unroll
      for (int r = 0; r < 4; r++) {
        const int m = mb + r;                  // chunk-local row
        const float v = sx[m] * swv * ((float)aHH[i][j][r] + (float)aX[i][j][r] * (1.f / 256.f)) + bv;
        if (TR) {
          const int lb = m >> 11, t = m & (T_ - 1);  // local batch, time
          out[(((size_t)lb << 10) + n) * T_ + t] = v;
        } else {
          out[(size_t)m * D_ + n] = v;
        }
      }
    }
  }
}

// ================= register-blocked FFT (radix [4,8,8,8]) =================
__device__ __forceinline__ int SWZ(int a) { return a ^ ((a >> 5) & 31); }
// output position of frequency k after DIF radices [4,8,8,8]
__device__ __forceinline__ int posk(int k) {
  return ((k & 3) << 9) | (((k >> 2) & 7) << 6) | (((k >> 5) & 7) << 3) | (k >> 8);
}

// forward 8-pt DFT (omega = e^{-2pi i/8}), natural-order in/out
__device__ __forceinline__ void dft8f(float* zr, float* zi) {
  const float C = 0.70710678118654752f;
  float sr = zr[0] + zr[4], si = zi[0] + zi[4];
  float tr = zr[0] - zr[4], ti = zi[0] - zi[4];
  float ur = zr[2] + zr[6], ui = zi[2] + zi[6];
  float vr = zr[2] - zr[6], vi = zi[2] - zi[6];
  const float e0r = sr + ur, e0i = si + ui;
  const float e2r = sr - ur, e2i = si - ui;
  const float e1r = tr + vi, e1i = ti - vr;   // t - i v
  const float e3r = tr - vi, e3i = ti + vr;   // t + i v
  sr = zr[1] + zr[5]; si = zi[1] + zi[5];
  tr = zr[1] - zr[5]; ti = zi[1] - zi[5];
  ur = zr[3] + zr[7]; ui = zi[3] + zi[7];
  vr = zr[3] - zr[7]; vi = zi[3] - zi[7];
  const float o0r = sr + ur, o0i = si + ui;
  const float o2r = sr - ur, o2i = si - ui;
  const float o1r = tr + vi, o1i = ti - vr;
  const float o3r = tr - vi, o3i = ti + vr;
  const float w1r = C * (o1r + o1i), w1i = C * (o1i - o1r);   // * (1-i)/sqrt2
  const float w2r = o2i,             w2i = -o2r;              // * (-i)
  const float w3r = C * (o3i - o3r), w3i = -C * (o3r + o3i);  // * (-1-i)/sqrt2
  zr[0] = e0r + o0r; zi[0] = e0i + o0i;
  zr[4] = e0r - o0r; zi[4] = e0i - o0i;
  zr[1] = e1r + w1r; zi[1] = e1i + w1i;
  zr[5] = e1r - w1r; zi[5] = e1i - w1i;
  zr[2] = e2r + w2r; zi[2] = e2i + w2i;
  zr[6] = e2r - w2r; zi[6] = e2i - w2i;
  zr[3] = e3r + w3r; zi[3] = e3i + w3i;
  zr[7] = e3r - w3r; zi[7] = e3i - w3i;
}

// inverse (unscaled) 8-pt DFT (omega = e^{+2pi i/8}), natural-order in/out
__device__ __forceinline__ void idft8(float* zr, float* zi) {
  const float C = 0.70710678118654752f;
  float sr = zr[0] + zr[4], si = zi[0] + zi[4];
  float tr = zr[0] - zr[4], ti = zi[0] - zi[4];
  float ur = zr[2] + zr[6], ui = zi[2] + zi[6];
  float vr = zr[2] - zr[6], vi = zi[2] - zi[6];
  const float e0r = sr + ur, e0i = si + ui;
  const float e2r = sr - ur, e2i = si - ui;
  const float e1r = tr - vi, e1i = ti + vr;   // t + i v
  const float e3r = tr + vi, e3i = ti - vr;   // t - i v
  sr = zr[1] + zr[5]; si = zi[1] + zi[5];
  tr = zr[1] - zr[5]; ti = zi[1] - zi[5];
  ur = zr[3] + zr[7]; ui = zi[3] + zi[7];
  vr = zr[3] - zr[7]; vi = zi[3] - zi[7];
  const float o0r = sr + ur, o0i = si + ui;
  const float o2r = sr - ur, o2i = si - ui;
  const float o1r = tr - vi, o1i = ti + vr;
  const float o3r = tr + vi, o3i = ti - vr;
  const float w1r = C * (o1r - o1i), w1i = C * (o1r + o1i);   // * (1+i)/sqrt2
  const float w2r = -o2i,            w2i = o2r;               // * (+i)
  const float w3r = -C * (o3r + o3i), w3i = C * (o3r - o3i);  // * (-1+i)/sqrt2
  zr[0] = e0r + o0r; zi[0] = e0i + o0i;
  zr[4] = e0r - o0r; zi[4] = e0i - o0i;
  zr[1] = e1r + w1r; zi[1] = e1i + w1i;
  zr[5] = e1r - w1r; zi[5] = e1i - w1i;
  zr[2] = e2r + w2r; zi[2] = e2i + w2i;
  zr[6] = e2r - w2r; zi[6] = e2i - w2i;
  zr[3] = e3r + w3r; zi[3] = e3i + w3i;
  zr[7] = e3r - w3r; zi[7] = e3i - w3i;
}

// z[m] *= w^m for m=1..7 (w given as cos,sin)
__device__ __forceinline__ void twmul7(float* zr, float* zi, float wc, float ws) {
  float cr = wc, ci = ws;
#pragma unroll
  for (int m = 1; m < 8; m++) {
    const float t = zr[m] * cr - zi[m] * ci;
    zi[m] = zr[m] * ci + zi[m] * cr;
    zr[m] = t;
    if (m < 7) { const float nr = cr * wc - ci * ws; ci = cr * ws + ci * wc; cr = nr; }
  }
}

// ---------- fused FFT + spectral filter + IFFT ----------
__global__ __launch_bounds__(256) void fft_spectral_k(float* __restrict__ QT,
                                                      const float* __restrict__ RT,
                                                      const float* __restrict__ alpha) {
  __shared__ float re[2048], im[2048];   // 16KB, swizzled slots
  const int tid = threadIdx.x;
  const int seq = blockIdx.x;  // lb*D + n
  const float av = alpha[seq & (QD_ - 1)];
  float* q = QT + (size_t)seq * T_;
  const float* r = RT + (size_t)seq * T_;
  const float NTPI = -6.28318530717958647692f;

  // saved forward twiddles (w = e^{-i th}); inverse reuses conj
  float w1c[2], w1s[2], w2c[2], w2s[2], w3c[2], w3s[2];
  float c64, s64, c8, s8;

  // ---- forward stage 1: radix-4 DIF, span 512; j in {tid, tid+256} ----
#pragma unroll
  for (int jj = 0; jj < 2; jj++) {
    const int j = tid + (jj << 8);
    const float x0r = q[j],        x0i = r[j];
    const float x1r = q[j + 512],  x1i = r[j + 512];
    const float x2r = q[j + 1024], x2i = r[j + 1024];
    const float x3r = q[j + 1536], x3i = r[j + 1536];
    float ws, wcs;
    __sincosf(NTPI * (float)j * (1.0f / 2048.0f), &ws, &wcs);
    const float w2r = wcs * wcs - ws * ws, w2i = 2.0f * wcs * ws;
    const float w3r = wcs * w2r - ws * w2i, w3i = wcs * w2i + ws * w2r;
    w1c[jj] = wcs; w1s[jj] = ws; w2c[jj] = w2r; w2s[jj] = w2i; w3c[jj] = w3r; w3s[jj] = w3i;
    const float ar = x0r + x2r, ai = x0i + x2i;
    const float br = x0r - x2r, bi = x0i - x2i;
    const float cr = x1r + x3r, ci = x1i + x3i;
    const float dr = x1r - x3r, di = x1i - x3i;
    re[SWZ(j)] = ar + cr;  im[SWZ(j)] = ai + ci;
    const float g1r = br + di, g1i = bi - dr;           // (b - i d) * w1
    re[SWZ(j + 512)] = g1r * wcs - g1i * ws;   im[SWZ(j + 512)] = g1r * ws + g1i * wcs;
    const float g2r = ar - cr, g2i = ai - ci;           // (a - c) * w2
    re[SWZ(j + 1024)] = g2r * w2r - g2i * w2i; im[SWZ(j + 1024)] = g2r * w2i + g2i * w2r;
    const float g3r = br - di, g3i = bi + dr;           // (b + i d) * w3
    re[SWZ(j + 1536)] = g3r * w3r - g3i * w3i; im[SWZ(j + 1536)] = g3r * w3i + g3i * w3r;
  }
  __syncthreads();

  float zr[8], zi[8];
  // ---- forward stage 2: radix-8, span 64 ----
  {
    const int base = ((tid >> 6) << 9) | (tid & 63);
#pragma unroll
    for (int p = 0; p < 8; p++) { const int ix = SWZ(base + (p << 6)); zr[p] = re[ix]; zi[p] = im[ix]; }
    dft8f(zr, zi);
    __sincosf(NTPI * (float)(tid & 63) * (1.0f / 512.0f), &s64, &c64);
    twmul7(zr, zi, c64, s64);
#pragma unroll
    for (int m = 0; m < 8; m++) { const int ix = SWZ(base + (m << 6)); re[ix] = zr[m]; im[ix] = zi[m]; }
  }
  __syncthreads();
  // ---- forward stage 3: radix-8, span 8 ----
  {
    const int base = ((tid >> 3) << 6) | (tid & 7);
#pragma unroll
    for (int p = 0; p < 8; p++) { const int ix = SWZ(base + (p << 3)); zr[p] = re[ix]; zi[p] = im[ix]; }
    dft8f(zr, zi);
    __sincosf(NTPI * (float)(tid & 7) * (1.0f / 64.0f), &s8, &c8);
    twmul7(zr, zi, c8, s8);
#pragma unroll
    for (int m = 0; m < 8; m++) { const int ix = SWZ(base + (m << 3)); re[ix] = zr[m]; im[ix] = zi[m]; }
  }
  __syncthreads();
  // ---- forward stage 4: radix-8, span 1 (no twiddle) ----
  {
    const int base = tid << 3;
#pragma unroll
    for (int p = 0; p < 8; p++) { const int ix = SWZ(base + p); zr[p] = re[ix]; zi[p] = im[ix]; }
    dft8f(zr, zi);
#pragma unroll
    for (int m = 0; m < 8; m++) { const int ix = SWZ(base + m); re[ix] = zr[m]; im[ix] = zi[m]; }
  }
  __syncthreads();

  // ---- spectral filter in digit-reversed domain ----
  // log(|z|+1e-8) ~= 0.5*log(|z|^2+1e-16): exact at |z|=0 and |z|>>eps; max phase
  // deviation ~1.5e-4 rad near |z|~1e-8 where |Qs*conj(Rs)| is itself ~1e-16.
  for (int f = tid; f <= 1024; f += 256) {
    const int fc = (2048 - f) & 2047;
    const int pf = SWZ(posk(f)), pc = SWZ(posk(fc));
    const float ar = re[pf], ai = im[pf];
    const float br = re[pc], bi = im[pc];
    const float qr = 0.5f * (ar + br), qi = 0.5f * (ai - bi);   // Qs[f]
    const float rr = 0.5f * (ai + bi), ri = -0.5f * (ar - br);  // Rs[f]
    const float q2 = qr * qr + qi * qi;
    const float r2 = rr * rr + ri * ri;
    const float ph = av * (atanf(0.5f * __logf(q2 + 1e-16f)) - atanf(0.5f * __logf(r2 + 1e-16f)));
    float sp, cp;
    __sincosf(ph, &sp, &cp);
    const float mr = qr * rr + qi * ri;   // Re(Qs conj(Rs))
    const float mi = qi * rr - qr * ri;   // Im(Qs conj(Rs))
    re[pf] = mr * cp - mi * sp;
    im[pf] = mr * sp + mi * cp;
    if (pc != pf) {                       // z[fc] = conj(M) e^{i ph}
      re[pc] = mr * cp + mi * sp;
      im[pc] = mr * sp - mi * cp;
    }
  }
  __syncthreads();

  // ---- inverse stage 4': radix-8, span 1 ----
  {
    const int base = tid << 3;
#pragma unroll
    for (int p = 0; p < 8; p++) { const int ix = SWZ(base + p); zr[p] = re[ix]; zi[p] = im[ix]; }
    idft8(zr, zi);
#pragma unroll
    for (int m = 0; m < 8; m++) { const int ix = SWZ(base + m); re[ix] = zr[m]; im[ix] = zi[m]; }
  }
  __syncthreads();
  // ---- inverse stage 3': conj twiddle (reused) then radix-8, span 8 ----
  {
    const int base = ((tid >> 3) << 6) | (tid & 7);
#pragma unroll
    for (int p = 0; p < 8; p++) { const int ix = SWZ(base + (p << 3)); zr[p] = re[ix]; zi[p] = im[ix]; }
    twmul7(zr, zi, c8, -s8);
    idft8(zr, zi);
#pragma unroll
    for (int m = 0; m < 8; m++) { const int ix = SWZ(base + (m << 3)); re[ix] = zr[m]; im[ix] = zi[m]; }
  }
  __syncthreads();
  // ---- inverse stage 2': conj twiddle (reused) then radix-8, span 64 ----
  {
    const int base = ((tid >> 6) << 9) | (tid & 63);
#pragma unroll
    for (int p = 0; p < 8; p++) { const int ix = SWZ(base + (p << 6)); zr[p] = re[ix]; zi[p] = im[ix]; }
    twmul7(zr, zi, c64, -s64);
    idft8(zr, zi);
#pragma unroll
    for (int m = 0; m < 8; m++) { const int ix = SWZ(base + (m << 6)); re[ix] = zr[m]; im[ix] = zi[m]; }
  }
  __syncthreads();
  // ---- inverse stage 1': conj twiddle (reused) + radix-4, span 512; write real/2048 ----
#pragma unroll
  for (int jj = 0; jj < 2; jj++) {
    const int j = tid + (jj << 8);
    const float x0r = re[SWZ(j)];
    const float x1r = re[SWZ(j + 512)],  x1i = im[SWZ(j + 512)];
    const float x2r = re[SWZ(j + 1024)], x2i = im[SWZ(j + 1024)];
    const float x3r = re[SWZ(j + 1536)], x3i = im[SWZ(j + 1536)];
    const float c1 = w1c[jj], s1 = w1s[jj];
    const float c2 = w2c[jj], s2 = w2s[jj];
    const float c3 = w3c[jj], s3 = w3s[jj];
    // multiply by conj(w^k) = (c, -s)
    const float z1r = x1r * c1 + x1i * s1, z1i = x1i * c1 - x1r * s1;
    const float z2r = x2r * c2 + x2i * s2;
    const float z3r = x3r * c3 + x3i * s3, z3i = x3i * c3 - x3r * s3;
    const float ar = x0r + z2r;
    const float br = x0r - z2r;
    const float cr = z1r + z3r;
    const float di = z1i - z3i;
    q[j]        = (ar + cr) * (1.0f / 2048.0f);
    q[j + 512]  = (br - di) * (1.0f / 2048.0f);   // y1 = b + i d
    q[j + 1024] = (ar - cr) * (1.0f / 2048.0f);
    q[j + 1536] = (br + di) * (1.0f / 2048.0f);   // y3 = b - i d
  }
}

// ---------- fused transpose + hamilton + sp_ln + gate + rot + residual + out_ln + quant ----
// inter in (CHB, D, T) layout; 8 t-rows per block staged via LDS; wave-level LN reductions.
// residual read from i8 planes with old sx; output re-quantized with new per-row sx.
__global__ __launch_bounds__(256) void fused2q_k(const float* __restrict__ inter,  // (CHB, D, T)
                                                 const float* __restrict__ Hb,     // (chm, D)
                                                 const float* __restrict__ spw, const float* __restrict__ spb,
                                                 const float* __restrict__ gate, const float* __restrict__ rot,
                                                 const float* __restrict__ ow, const float* __restrict__ ob,
                                                 I8* __restrict__ xh8, I8* __restrict__ xl8,
                                                 float* __restrict__ sxc) {
  __shared__ float ti[8 * 1028];   // 8 rows, +4 pad per row breaks bank aliasing
  const int tid = threadIdx.x;
  const int m0 = blockIdx.x * 8;          // chunk-local row base (multiple of 8)
  const int lb = m0 >> 11;                // local batch within chunk
  const int t0 = m0 & (T_ - 1);
  // ---- stage 8t x 1024n tile: float4 along t ----
  {
    const int tq = (tid & 1) * 4;         // 0 or 4
    const int nb = tid >> 1;              // 0..127
#pragma unroll
    for (int p = 0; p < 8; p++) {
      const int n = p * 128 + nb;
      const float4 v = *(const float4*)(inter + ((size_t)((lb << 10) | n)) * T_ + t0 + tq);
      ti[(tq + 0) * 1028 + n] = fixf(v.x);
      ti[(tq + 1) * 1028 + n] = fixf(v.y);
      ti[(tq + 2) * 1028 + n] = fixf(v.z);
      ti[(tq + 3) * 1028 + n] = fixf(v.w);
    }
  }
  __syncthreads();
  const int wv = tid >> 6, lane = tid & 63;
  float rr_[16];
#pragma unroll
  for (int i = 0; i < 16; i++) rr_[i] = rot[i];
#pragma unroll
  for (int rwi = 0; rwi < 2; rwi++) {
    const int tt = wv * 2 + rwi;
    const int m = m0 + tt;
    const size_t mb = (size_t)m * D_;
    const float sxold = sxc[m];
    float o[4][4];  // [kq][component]
#pragma unroll
    for (int kq = 0; kq < 4; kq++) {
      float iv[4], hv[4];
#pragma unroll
      for (int c2 = 0; c2 < 4; c2++) {
        iv[c2] = ti[tt * 1028 + (c2 * 4 + kq) * 64 + lane];
        hv[c2] = fixf(Hb[mb + (size_t)(c2 * 4 + kq) * 64 + lane]);
      }
      o[kq][0] = iv[0] * hv[0] - iv[1] * hv[1] - iv[2] * hv[2] - iv[3] * hv[3];
      o[kq][1] = iv[0] * hv[1] + iv[1] * hv[0] + iv[2] * hv[3] - iv[3] * hv[2];
      o[kq][2] = iv[0] * hv[2] - iv[1] * hv[3] + iv[2] * hv[0] + iv[3] * hv[1];
      o[kq][3] = iv[0] * hv[3] + iv[1] * hv[2] - iv[2] * hv[1] + iv[3] * hv[0];
    }
    float s = 0.f, ss = 0.f;
#pragma unroll
    for (int kq = 0; kq < 4; kq++)
#pragma unroll
      for (int c2 = 0; c2 < 4; c2++) { s += o[kq][c2]; ss += o[kq][c2] * o[kq][c2]; }
#pragma unroll
    for (int off = 32; off > 0; off >>= 1) { s += __shfl_xor(s, off); ss += __shfl_xor(ss, off); }
    const float mean = s * (1.0f / 1024.0f);
    const float rstd = rsqrtf(ss * (1.0f / 1024.0f) - mean * mean + 1e-5f);
    float y[4][4];  // [j][kq]
#pragma unroll
    for (int kq = 0; kq < 4; kq++) {
      const int qd = kq * 64 + lane;
      const float g = gate[qd];
      float xf[4];
#pragma unroll
      for (int c2 = 0; c2 < 4; c2++)
        xf[c2] = ((o[kq][c2] - mean) * rstd * spw[c2 * 256 + qd] + spb[c2 * 256 + qd]) * g;
#pragma unroll
      for (int j = 0; j < 4; j++) {
        const float a = rr_[j * 4 + 0] * xf[0] + rr_[j * 4 + 1] * xf[1]
                      + rr_[j * 4 + 2] * xf[2] + rr_[j * 4 + 3] * xf[3];
        const size_t idx = mb + j * 256 + qd;
        const float res = sxold * ((float)xh8[idx] + (float)xl8[idx] * (1.f / 256.f));
        y[j][kq] = a + res;
      }
    }
    float s2 = 0.f, ss2 = 0.f;
#pragma unroll
    for (int j = 0; j < 4; j++)
#pragma unroll
      for (int kq = 0; kq < 4; kq++) { s2 += y[j][kq]; ss2 += y[j][kq] * y[j][kq]; }
#pragma unroll
    for (int off = 32; off > 0; off >>= 1) { s2 += __shfl_xor(s2, off); ss2 += __shfl_xor(ss2, off); }
    const float mean2 = s2 * (1.0f / 1024.0f);
    const float rstd2 = rsqrtf(ss2 * (1.0f / 1024.0f) - mean2 * mean2 + 1e-5f);
    float vout[4][4];
    float mx = 0.f;
#pragma unroll
    for (int j = 0; j < 4; j++)
#pragma unroll
      for (int kq = 0; kq < 4; kq++) {
        const int qd = kq * 64 + lane;
        const float v = (y[j][kq] - mean2) * rstd2 * ow[j * 256 + qd] + ob[j * 256 + qd];
        vout[j][kq] = v;
        mx = fmaxf(mx, fabsf(v));
      }
#pragma unroll
    for (int off = 32; off > 0; off >>= 1) mx = fmaxf(mx, __shfl_xor(mx, off));
    const float mxg = fmaxf(mx, 1e-30f);
    const float sxn = mxg * (1.f / 127.f);
    const float inv = 127.f / mxg;
    if (lane == 0) sxc[m] = sxn;
#pragma unroll
    for (int j = 0; j < 4; j++)
#pragma unroll
      for (int kq = 0; kq < 4; kq++) {
        const int qd = kq * 64 + lane;
        const size_t idx = mb + j * 256 + qd;
        int qh, ql;
        quant2(vout[j][kq], inv, qh, ql);
        xh8[idx] = (I8)qh;
        xl8[idx] = (I8)ql;
      }
  }
}

// ---------- mean over T (partials + atomics; pooled must be zeroed) ----------
__global__ __launch_bounds__(256) void poolq_k(const I8* __restrict__ xh, const I8* __restrict__ xl,
                                               const float* __restrict__ sx,
                                               float* __restrict__ pooled) {
  const int b = blockIdx.z;
  const int d = blockIdx.x * 256 + threadIdx.x;
  const int t0 = blockIdx.y * 256;
  float s = 0.f;
  for (int t = t0; t < t0 + 256; t++) {
    const int row = b * T_ + t;
    const size_t idx = (size_t)row * D_ + d;
    s += sx[row] * ((float)xh[idx] + (float)xl[idx] * (1.f / 256.f));
  }
  atomicAdd(&pooled[b * D_ + d], s);
}

// ---------- classifier LN ----------
__global__ __launch_bounds__(256) void clsln_k(const float* __restrict__ pooled, const float* __restrict__ w,
                                               const float* __restrict__ bias, float* __restrict__ h) {
  __shared__ float red[8];
  const int b = blockIdx.x;
  const int d = threadIdx.x;
  float v[4];
#pragma unroll
  for (int j = 0; j < 4; j++) v[j] = fixf(pooled[b * D_ + j * 256 + d]) * (1.0f / (float)T_);
  float s = v[0] + v[1] + v[2] + v[3];
  float ss = v[0] * v[0] + v[1] * v[1] + v[2] * v[2] + v[3] * v[3];
  breduce2(s, ss, red);
  const float mean = s * (1.0f / (float)D_);
  const float rstd = rsqrtf(ss * (1.0f / (float)D_) - mean * mean + 1e-5f);
#pragma unroll
  for (int j = 0; j < 4; j++)
    h[b * D_ + j * 256 + d] = (v[j] - mean) * rstd * w[j * 256 + d] + bias[j * 256 + d];
}

// ---------- classifier GEMM: one wave per (b, n) ----------
__global__ __launch_bounds__(256) void cls_k(const float* __restrict__ h, const float* __restrict__ W,
                                             const float* __restrict__ cb, float* __restrict__ out) {
  const int wv = blockIdx.x * 4 + (threadIdx.x >> 6);
  const int lane = threadIdx.x & 63;
  const int b = wv / NCLS_;
  const int n = wv - b * NCLS_;
  const float* hb = h + b * D_;
  const float* wr = W + (size_t)n * D_;
  float s = 0.f;
  for (int j = lane; j < D_; j += 64) s += hb[j] * wr[j];
#pragma unroll
  for (int off = 32; off > 0; off >>= 1) s += __shfl_down(s, off);
  if (lane == 0) out[b * NCLS_ + n] = fixf(s + cb[n]);
}

// ---------- launch ----------
extern "C" void kernel_launch(void* const* d_in, const int* in_sizes, int n_in,
                              void* d_out, int out_size, void* d_ws, size_t ws_size,
                              hipStream_t stream) {
  (void)in_sizes; (void)n_in; (void)out_size;
  const int* tokens = (const int*)d_in[0];
  const float* emb = (const float*)d_in[1];
  const float* pos = (const float*)d_in[2];
  const float* Wq = (const float*)d_in[3];
  const float* bq = (const float*)d_in[4];
  const float* Wr = (const float*)d_in[5];
  const float* br = (const float*)d_in[6];
  const float* Wh = (const float*)d_in[7];
  const float* bh = (const float*)d_in[8];
  const float* alpha = (const float*)d_in[9];
  const float* spw = (const float*)d_in[10];
  const float* spb = (const float*)d_in[11];
  const float* gate = (const float*)d_in[12];
  const float* rot = (const float*)d_in[13];
  const float* outw = (const float*)d_in[14];
  const float* outb = (const float*)d_in[15];
  const float* clw = (const float*)d_in[16];
  const float* clb = (const float*)d_in[17];
  const float* clsW = (const float*)d_in[18];
  const float* clsb = (const float*)d_in[19];
  float* out = (float*)d_out;

  // ---- adaptive footprint from ws_size ----
  // fixed: xh8 16MB + xl8 16MB + Wh8 3MB + Wl8 3MB + sx/sw 1MB = 39MB
  // per-chunk f32: 3 * CHB * 8MB  (CHB=4: 96MB -> 135 total; CHB=2: 87; CHB=1: 63)
  const size_t MB = 1048576;
  int CHB;
  if      (ws_size >= 136 * MB) CHB = 4;
  else if (ws_size >=  88 * MB) CHB = 2;
  else                          CHB = 1;
  const int nchunks = B_ / CHB;
  const int chm = CHB * T_;
  const size_t chunkf = (size_t)CHB * T_ * D_ * 4;

  char* ws = (char*)d_ws;
  I8* xh8 = (I8*)ws;                       // 16 MB
  I8* xl8 = (I8*)(ws + 16 * MB);           // 16 MB
  I8* Wh8 = (I8*)(ws + 32 * MB);           // 3 MB (Q,R,H)
  I8* Wl8 = (I8*)(ws + 35 * MB);           // 3 MB
  float* sx = (float*)(ws + 38 * MB);      // 64 KB (per-row x scales)
  float* sw = (float*)(ws + 38 * MB + 65536);  // 12 KB (per-row W scales, 3 secs)
  char* fb = ws + 39 * MB;
  float* QTc = (float*)fb;
  float* RTc = (float*)(fb + chunkf);
  float* Hc  = (float*)(fb + 2 * chunkf);
  float* pooled = (float*)fb;              // reuse after layers
  float* hbuf   = (float*)(fb + 32768);

  embedq_k<<<M_, 256, 0, stream>>>(tokens, emb, pos, xh8, xl8, sx);

  const dim3 gemm_grid(24, chm / 128);
  for (int l = 0; l < L_; l++) {
    const size_t wo = (size_t)l * DD_;
    wsplitq_k<<<3072, 256, 0, stream>>>(Wq + wo, Wr + wo, Wh + wo, Wh8, Wl8, sw);
    for (int c = 0; c < nchunks; c++) {
      const size_t xoff = (size_t)c * chm * D_;
      gemm3q_k<<<gemm_grid, 256, 0, stream>>>(xh8 + xoff, xl8 + xoff, Wh8, Wl8,
                                              sx + (size_t)c * chm, sw,
                                              bq + l * D_, br + l * D_, bh + l * D_,
                                              QTc, RTc, Hc);
      fft_spectral_k<<<CHB * D_, 256, 0, stream>>>(QTc, RTc, alpha + l * QD_);
      fused2q_k<<<chm / 8, 256, 0, stream>>>(QTc, Hc, spw + l * D_, spb + l * D_,
                                             gate + l * QD_, rot + l * 16,
                                             outw + l * D_, outb + l * D_,
                                             xh8 + xoff, xl8 + xoff, sx + (size_t)c * chm);
    }
  }

  hipMemsetAsync(pooled, 0, B_ * D_ * sizeof(float), stream);
  poolq_k<<<dim3(4, 8, 8), 256, 0, stream>>>(xh8, xl8, sx, pooled);
  clsln_k<<<B_, 256, 0, stream>>>(pooled, clw, clb, hbuf);
  cls_k<<<(B_ * NCLS_) / 4, 256, 0, stream>>>(hbuf, clsW, clsb, out);
}

// Round 14
// 1799.194 us; speedup vs baseline: 1.0066x; 1.0066x over previous
//
#include <hip/hip_runtime.h>

typedef signed char I8;
typedef __attribute__((ext_vector_type(4))) int i32x4;
typedef __attribute__((ext_vector_type(4))) float f32x4;

#define B_   8
#define T_   2048
#define D_   1024
#define QD_  256
#define L_   4
#define M_   (B_ * T_)      // 16384
#define NCLS_ 1000
#define DD_  (D_ * D_)

// ---------- helpers ----------
__device__ __forceinline__ float fixf(float v) {
  unsigned u = __float_as_uint(v);
  return ((u & 0x7F800000u) == 0x7F800000u) ? 0.f : v;
}
__device__ __forceinline__ void glds16(const void* g, void* l) {
  __builtin_amdgcn_global_load_lds((const __attribute__((address_space(1))) void*)g,
                                   (__attribute__((address_space(3))) void*)l, 16, 0, 0);
}
__device__ __forceinline__ int clampi(int q) { return q < -128 ? -128 : (q > 127 ? 127 : q); }
// quantize v (|v| <= 127/inv) to 16-bit fixed point: v ~= (qh + ql/256)/inv
__device__ __forceinline__ void quant2(float v, float inv, int& qh, int& ql) {
  const float t = v * inv;
  int h = clampi((int)rintf(t));
  const float r = t - (float)h;
  int l = clampi((int)rintf(r * 256.f));
  qh = h; ql = l;
}
// fast atan: 4-term minimax on [0,1] + reciprocal fold; |err| <= ~1e-4 rad
__device__ __forceinline__ float fatan(float x) {
  const float ax = fabsf(x);
  const bool big = ax > 1.f;
  const float z = big ? 1.f / ax : ax;
  const float z2 = z * z;
  const float p = z * (0.99986f + z2 * (-0.33030f + z2 * (0.18014f + z2 * (-0.085133f))));
  const float r = big ? 1.57079632679f - p : p;
  return copysignf(r, x);
}
// block=256 (4 waves): reduce two sums across block
__device__ __forceinline__ void breduce2(float& a, float& b, float* buf) {
#pragma unroll
  for (int off = 32; off > 0; off >>= 1) { a += __shfl_down(a, off); b += __shfl_down(b, off); }
  const int lane = threadIdx.x & 63, w = threadIdx.x >> 6;
  __syncthreads();
  if (lane == 0) { buf[w] = a; buf[4 + w] = b; }
  __syncthreads();
  a = buf[0] + buf[1] + buf[2] + buf[3];
  b = buf[4] + buf[5] + buf[6] + buf[7];
}
// block=256: max across block
__device__ __forceinline__ float bmaxall(float a, float* buf) {
#pragma unroll
  for (int off = 32; off > 0; off >>= 1) a = fmaxf(a, __shfl_down(a, off));
  const int lane = threadIdx.x & 63, w = threadIdx.x >> 6;
  __syncthreads();
  if (lane == 0) buf[w] = a;
  __syncthreads();
  return fmaxf(fmaxf(buf[0], buf[1]), fmaxf(buf[2], buf[3]));
}

// ---------- weight quant: f32 -> i8 hi/lo planes + per-row scale, Q+R+H fused ----------
__global__ __launch_bounds__(256) void wsplitq_k(const float* __restrict__ Wq,
                                                 const float* __restrict__ Wr,
                                                 const float* __restrict__ Wh,
                                                 I8* __restrict__ hi, I8* __restrict__ lo,
                                                 float* __restrict__ sw) {
  __shared__ float red[4];
  const int sec = blockIdx.x >> 10;
  const int n = blockIdx.x & 1023;
  const float* w = (sec == 0) ? Wq : (sec == 1) ? Wr : Wh;
  const int c = threadIdx.x * 4;
  const float4 v = *(const float4*)(w + (size_t)n * D_ + c);
  const float vv[4] = {v.x, v.y, v.z, v.w};
  float mx = fmaxf(fmaxf(fabsf(v.x), fabsf(v.y)), fmaxf(fabsf(v.z), fabsf(v.w)));
  mx = bmaxall(mx, red);
  const float s = fmaxf(mx, 1e-30f) * (1.f / 127.f);
  if (threadIdx.x == 0) sw[sec * D_ + n] = s;
  const float inv = 127.f / fmaxf(mx, 1e-30f);
  unsigned ph = 0, pl = 0;
#pragma unroll
  for (int j = 0; j < 4; j++) {
    int qh, ql;
    quant2(vv[j], inv, qh, ql);
    ph |= ((unsigned)(unsigned char)(I8)qh) << (8 * j);
    pl |= ((unsigned)(unsigned char)(I8)ql) << (8 * j);
  }
  const size_t o = (size_t)sec * DD_ + (size_t)n * D_ + c;
  *(unsigned*)(hi + o) = ph;
  *(unsigned*)(lo + o) = pl;
}

// ---------- embed: x = embed[tokens] + pos -> i8 hi/lo planes + per-row scale ----------
__global__ __launch_bounds__(256) void embedq_k(const int* __restrict__ tok,
                                                const float* __restrict__ emb,
                                                const float* __restrict__ pos,
                                                I8* __restrict__ xh, I8* __restrict__ xl,
                                                float* __restrict__ sx) {
  __shared__ float red[4];
  const int m = blockIdx.x;
  const int t = m & (T_ - 1);
  const int tk = tok[m];
  const int c = threadIdx.x * 4;
  const float* e = emb + (size_t)tk * D_ + c;
  const float* p = pos + (size_t)t * D_ + c;
  float v[4];
  float mx = 0.f;
#pragma unroll
  for (int i = 0; i < 4; i++) { v[i] = e[i] + p[i]; mx = fmaxf(mx, fabsf(v[i])); }
  mx = bmaxall(mx, red);
  const float s = fmaxf(mx, 1e-30f) * (1.f / 127.f);
  if (threadIdx.x == 0) sx[m] = s;
  const float inv = 127.f / fmaxf(mx, 1e-30f);
  unsigned ph = 0, pl = 0;
#pragma unroll
  for (int i = 0; i < 4; i++) {
    int qh, ql;
    quant2(v[i], inv, qh, ql);
    ph |= ((unsigned)(unsigned char)(I8)qh) << (8 * i);
    pl |= ((unsigned)(unsigned char)(I8)ql) << (8 * i);
  }
  const size_t o = (size_t)m * D_ + c;
  *(unsigned*)(xh + o) = ph;
  *(unsigned*)(xl + o) = pl;
}

// ---------- GEMM (i8 fixed-point): C = sx[m]*sw[n]*(hh + cross/256) + bias, Q+R+H fused ----
// 128x128 tile, BK=64 i8, 4 waves of 64x64, mfma_i32_16x16x64_i8.
// Double-buffered LDS + counted vmcnt(8).
// grid.x = 24: 0-7 -> Q (TR), 8-15 -> R (TR), 16-23 -> H (natural).
__global__ __launch_bounds__(256, 2) void gemm3q_k(const I8* __restrict__ Ahi,
                                                   const I8* __restrict__ Alo,
                                                   const I8* __restrict__ Whi,
                                                   const I8* __restrict__ Wlo,
                                                   const float* __restrict__ sx,
                                                   const float* __restrict__ sw,
                                                   const float* __restrict__ bq,
                                                   const float* __restrict__ br,
                                                   const float* __restrict__ bh,
                                                   float* __restrict__ outQ,
                                                   float* __restrict__ outR,
                                                   float* __restrict__ outH) {
  __shared__ __align__(16) I8 lds[65536];  // 2 buffers x 32KB
  char* sbase = (char*)lds;
  const int tid = threadIdx.x;
  const int lane = tid & 63;
  const int wave = tid >> 6;
  const int wr = wave >> 1, wc = wave & 1;
  const int sec = blockIdx.x >> 3;
  const int n0 = (blockIdx.x & 7) * 128;
  const int m0 = blockIdx.y * 128;
  const I8* Bhi = Whi + (size_t)sec * DD_;
  const I8* Blo = Wlo + (size_t)sec * DD_;
  const float* bias = (sec == 0) ? bq : (sec == 1) ? br : bh;
  float* out = (sec == 0) ? outQ : (sec == 1) ? outR : outH;
  const bool TR = sec < 2;

  i32x4 aHH[4][4], aX[4][4];
#pragma unroll
  for (int i = 0; i < 4; i++)
#pragma unroll
    for (int j = 0; j < 4; j++) { aHH[i][j] = (i32x4){0, 0, 0, 0}; aX[i][j] = (i32x4){0, 0, 0, 0}; }

  const int lrow = tid >> 2;            // 0..63
  const int lcolb = (tid & 3) * 16;     // bytes within 64B k-row
  const char* gah = (const char*)Ahi + (size_t)(m0 + lrow) * D_ + lcolb;
  const char* gal = (const char*)Alo + (size_t)(m0 + lrow) * D_ + lcolb;
  const char* gbh = (const char*)Bhi + (size_t)(n0 + lrow) * D_ + lcolb;
  const char* gbl = (const char*)Blo + (size_t)(n0 + lrow) * D_ + lcolb;

  const int koff = (lane >> 4) * 16;                 // byte k-offset of fragment
  const int mA = (wr * 64 + (lane & 15)) * 64;       // byte row base (A)
  const int nB = (wc * 64 + (lane & 15)) * 64;       // byte row base (B)

  // ---- prologue: stage K-tile 0 into buffer 0, drain fully ----
  {
    char* d = sbase + tid * 16;
    glds16(gah, d);
    glds16(gah + 64 * D_, d + 4096);
    glds16(gal, d + 8192);
    glds16(gal + 64 * D_, d + 12288);
    glds16(gbh, d + 16384);
    glds16(gbh + 64 * D_, d + 20480);
    glds16(gbl, d + 24576);
    glds16(gbl + 64 * D_, d + 28672);
    gah += 64; gal += 64; gbh += 64; gbl += 64;
  }
  asm volatile("s_waitcnt vmcnt(0)" ::: "memory");
  __builtin_amdgcn_s_barrier();

  int cur = 0;
  for (int kk = 0; kk < 1024; kk += 64) {
    if (kk < 1024 - 64) {
      char* d = sbase + (cur ^ 1) * 32768 + tid * 16;
      glds16(gah, d);
      glds16(gah + 64 * D_, d + 4096);
      glds16(gal, d + 8192);
      glds16(gal + 64 * D_, d + 12288);
      glds16(gbh, d + 16384);
      glds16(gbh + 64 * D_, d + 20480);
      glds16(gbl, d + 24576);
      glds16(gbl + 64 * D_, d + 28672);
      gah += 64; gal += 64; gbh += 64; gbl += 64;
      asm volatile("s_waitcnt vmcnt(8)" ::: "memory");
    } else {
      asm volatile("s_waitcnt vmcnt(0)" ::: "memory");
    }
    __builtin_amdgcn_s_barrier();
    const char* sb = sbase + cur * 32768;
    i32x4 ah[4], al[4], bh2[4], bl2[4];
#pragma unroll
    for (int i = 0; i < 4; i++) {
      const char* pa = sb + mA + i * 1024 + koff;
      ah[i] = *(const i32x4*)pa;
      al[i] = *(const i32x4*)(pa + 8192);
    }
#pragma unroll
    for (int j = 0; j < 4; j++) {
      const char* pb = sb + 16384 + nB + j * 1024 + koff;
      bh2[j] = *(const i32x4*)pb;
      bl2[j] = *(const i32x4*)(pb + 8192);
    }
#pragma unroll
    for (int i = 0; i < 4; i++)
#pragma unroll
      for (int j = 0; j < 4; j++) {
        aHH[i][j] = __builtin_amdgcn_mfma_i32_16x16x64_i8(ah[i], bh2[j], aHH[i][j], 0, 0, 0);
        aX[i][j]  = __builtin_amdgcn_mfma_i32_16x16x64_i8(ah[i], bl2[j], aX[i][j], 0, 0, 0);
        aX[i][j]  = __builtin_amdgcn_mfma_i32_16x16x64_i8(al[i], bh2[j], aX[i][j], 0, 0, 0);
      }
    __builtin_amdgcn_s_barrier();
    cur ^= 1;
  }

#pragma unroll
  for (int j = 0; j < 4; j++) {
    const int n = n0 + wc * 64 + j * 16 + (lane & 15);
    const float swv = sw[sec * D_ + n];
    const float bv = bias[n];
#pragma unroll
    for (int i = 0; i < 4; i++) {
      const int mb = m0 + wr * 64 + i * 16 + ((lane >> 4) << 2);
      const float4 sx4 = *(const float4*)(sx + mb);
      const float sxa[4] = {sx4.x, sx4.y, sx4.z, sx4.w};
#pragma unroll
      for (int r = 0; r < 4; r++) {
        const int m = mb + r;                  // chunk-local row
        const float v = sxa[r] * swv * ((float)aHH[i][j][r] + (float)aX[i][j][r] * (1.f / 256.f)) + bv;
        if (TR) {
          const int lb = m >> 11, t = m & (T_ - 1);  // local batch, time
          out[(((size_t)lb << 10) + n) * T_ + t] = v;
        } else {
          out[(size_t)m * D_ + n] = v;
        }
      }
    }
  }
}

// ================= register-blocked FFT (radix [4,8,8,8]) =================
__device__ __forceinline__ int SWZ(int a) { return a ^ ((a >> 5) & 31); }
__device__ __forceinline__ int posk(int k) {
  return ((k & 3) << 9) | (((k >> 2) & 7) << 6) | (((k >> 5) & 7) << 3) | (k >> 8);
}

// forward 8-pt DFT (omega = e^{-2pi i/8})
__device__ __forceinline__ void dft8f(float* zr, float* zi) {
  const float C = 0.70710678118654752f;
  float sr = zr[0] + zr[4], si = zi[0] + zi[4];
  float tr = zr[0] - zr[4], ti = zi[0] - zi[4];
  float ur = zr[2] + zr[6], ui = zi[2] + zi[6];
  float vr = zr[2] - zr[6], vi = zi[2] - zi[6];
  const float e0r = sr + ur, e0i = si + ui;
  const float e2r = sr - ur, e2i = si - ui;
  const float e1r = tr + vi, e1i = ti - vr;
  const float e3r = tr - vi, e3i = ti + vr;
  sr = zr[1] + zr[5]; si = zi[1] + zi[5];
  tr = zr[1] - zr[5]; ti = zi[1] - zi[5];
  ur = zr[3] + zr[7]; ui = zi[3] + zi[7];
  vr = zr[3] - zr[7]; vi = zi[3] - zi[7];
  const float o0r = sr + ur, o0i = si + ui;
  const float o2r = sr - ur, o2i = si - ui;
  const float o1r = tr + vi, o1i = ti - vr;
  const float o3r = tr - vi, o3i = ti + vr;
  const float w1r = C * (o1r + o1i), w1i = C * (o1i - o1r);
  const float w2r = o2i,             w2i = -o2r;
  const float w3r = C * (o3i - o3r), w3i = -C * (o3r + o3i);
  zr[0] = e0r + o0r; zi[0] = e0i + o0i;
  zr[4] = e0r - o0r; zi[4] = e0i - o0i;
  zr[1] = e1r + w1r; zi[1] = e1i + w1i;
  zr[5] = e1r - w1r; zi[5] = e1i - w1i;
  zr[2] = e2r + w2r; zi[2] = e2i + w2i;
  zr[6] = e2r - w2r; zi[6] = e2i - w2i;
  zr[3] = e3r + w3r; zi[3] = e3i + w3i;
  zr[7] = e3r - w3r; zi[7] = e3i - w3i;
}

// inverse (unscaled) 8-pt DFT (omega = e^{+2pi i/8})
__device__ __forceinline__ void idft8(float* zr, float* zi) {
  const float C = 0.70710678118654752f;
  float sr = zr[0] + zr[4], si = zi[0] + zi[4];
  float tr = zr[0] - zr[4], ti = zi[0] - zi[4];
  float ur = zr[2] + zr[6], ui = zi[2] + zi[6];
  float vr = zr[2] - zr[6], vi = zi[2] - zi[6];
  const float e0r = sr + ur, e0i = si + ui;
  const float e2r = sr - ur, e2i = si - ui;
  const float e1r = tr - vi, e1i = ti + vr;
  const float e3r = tr + vi, e3i = ti - vr;
  sr = zr[1] + zr[5]; si = zi[1] + zi[5];
  tr = zr[1] - zr[5]; ti = zi[1] - zi[5];
  ur = zr[3] + zr[7]; ui = zi[3] + zi[7];
  vr = zr[3] - zr[7]; vi = zi[3] - zi[7];
  const float o0r = sr + ur, o0i = si + ui;
  const float o2r = sr - ur, o2i = si - ui;
  const float o1r = tr - vi, o1i = ti + vr;
  const float o3r = tr + vi, o3i = ti - vr;
  const float w1r = C * (o1r - o1i), w1i = C * (o1r + o1i);
  const float w2r = -o2i,            w2i = o2r;
  const float w3r = -C * (o3r + o3i), w3i = C * (o3r - o3i);
  zr[0] = e0r + o0r; zi[0] = e0i + o0i;
  zr[4] = e0r - o0r; zi[4] = e0i - o0i;
  zr[1] = e1r + w1r; zi[1] = e1i + w1i;
  zr[5] = e1r - w1r; zi[5] = e1i - w1i;
  zr[2] = e2r + w2r; zi[2] = e2i + w2i;
  zr[6] = e2r - w2r; zi[6] = e2i - w2i;
  zr[3] = e3r + w3r; zi[3] = e3i + w3i;
  zr[7] = e3r - w3r; zi[7] = e3i - w3i;
}

// z[m] *= w^m for m=1..7
__device__ __forceinline__ void twmul7(float* zr, float* zi, float wc, float ws) {
  float cr = wc, ci = ws;
#pragma unroll
  for (int m = 1; m < 8; m++) {
    const float t = zr[m] * cr - zi[m] * ci;
    zi[m] = zr[m] * ci + zi[m] * cr;
    zr[m] = t;
    if (m < 7) { const float nr = cr * wc - ci * ws; ci = cr * ws + ci * wc; cr = nr; }
  }
}

// ---------- fused FFT + spectral filter + IFFT ----------
__global__ __launch_bounds__(256) void fft_spectral_k(float* __restrict__ QT,
                                                      const float* __restrict__ RT,
                                                      const float* __restrict__ alpha) {
  __shared__ float re[2048], im[2048];   // 16KB, swizzled slots
  const int tid = threadIdx.x;
  const int seq = blockIdx.x;  // lb*D + n
  const float av = alpha[seq & (QD_ - 1)];
  float* q = QT + (size_t)seq * T_;
  const float* r = RT + (size_t)seq * T_;
  const float NTPI = -6.28318530717958647692f;

  float w1c[2], w1s[2], w2c[2], w2s[2], w3c[2], w3s[2];
  float c64, s64, c8, s8;

  // ---- forward stage 1: radix-4 DIF, span 512 ----
#pragma unroll
  for (int jj = 0; jj < 2; jj++) {
    const int j = tid + (jj << 8);
    const float x0r = q[j],        x0i = r[j];
    const float x1r = q[j + 512],  x1i = r[j + 512];
    const float x2r = q[j + 1024], x2i = r[j + 1024];
    const float x3r = q[j + 1536], x3i = r[j + 1536];
    float ws, wcs;
    __sincosf(NTPI * (float)j * (1.0f / 2048.0f), &ws, &wcs);
    const float w2r = wcs * wcs - ws * ws, w2i = 2.0f * wcs * ws;
    const float w3r = wcs * w2r - ws * w2i, w3i = wcs * w2i + ws * w2r;
    w1c[jj] = wcs; w1s[jj] = ws; w2c[jj] = w2r; w2s[jj] = w2i; w3c[jj] = w3r; w3s[jj] = w3i;
    const float ar = x0r + x2r, ai = x0i + x2i;
    const float br = x0r - x2r, bi = x0i - x2i;
    const float cr = x1r + x3r, ci = x1i + x3i;
    const float dr = x1r - x3r, di = x1i - x3i;
    re[SWZ(j)] = ar + cr;  im[SWZ(j)] = ai + ci;
    const float g1r = br + di, g1i = bi - dr;
    re[SWZ(j + 512)] = g1r * wcs - g1i * ws;   im[SWZ(j + 512)] = g1r * ws + g1i * wcs;
    const float g2r = ar - cr, g2i = ai - ci;
    re[SWZ(j + 1024)] = g2r * w2r - g2i * w2i; im[SWZ(j + 1024)] = g2r * w2i + g2i * w2r;
    const float g3r = br - di, g3i = bi + dr;
    re[SWZ(j + 1536)] = g3r * w3r - g3i * w3i; im[SWZ(j + 1536)] = g3r * w3i + g3i * w3r;
  }
  __syncthreads();

  float zr[8], zi[8];
  // ---- forward stage 2: radix-8, span 64 ----
  {
    const int base = ((tid >> 6) << 9) | (tid & 63);
#pragma unroll
    for (int p = 0; p < 8; p++) { const int ix = SWZ(base + (p << 6)); zr[p] = re[ix]; zi[p] = im[ix]; }
    dft8f(zr, zi);
    __sincosf(NTPI * (float)(tid & 63) * (1.0f / 512.0f), &s64, &c64);
    twmul7(zr, zi, c64, s64);
#pragma unroll
    for (int m = 0; m < 8; m++) { const int ix = SWZ(base + (m << 6)); re[ix] = zr[m]; im[ix] = zi[m]; }
  }
  __syncthreads();
  // ---- forward stage 3: radix-8, span 8 ----
  {
    const int base = ((tid >> 3) << 6) | (tid & 7);
#pragma unroll
    for (int p = 0; p < 8; p++) { const int ix = SWZ(base + (p << 3)); zr[p] = re[ix]; zi[p] = im[ix]; }
    dft8f(zr, zi);
    __sincosf(NTPI * (float)(tid & 7) * (1.0f / 64.0f), &s8, &c8);
    twmul7(zr, zi, c8, s8);
#pragma unroll
    for (int m = 0; m < 8; m++) { const int ix = SWZ(base + (m << 3)); re[ix] = zr[m]; im[ix] = zi[m]; }
  }
  __syncthreads();
  // ---- forward stage 4: radix-8, span 1 ----
  {
    const int base = tid << 3;
#pragma unroll
    for (int p = 0; p < 8; p++) { const int ix = SWZ(base + p); zr[p] = re[ix]; zi[p] = im[ix]; }
    dft8f(zr, zi);
#pragma unroll
    for (int m = 0; m < 8; m++) { const int ix = SWZ(base + m); re[ix] = zr[m]; im[ix] = zi[m]; }
  }
  __syncthreads();

  // ---- spectral filter in digit-reversed domain ----
  for (int f = tid; f <= 1024; f += 256) {
    const int fc = (2048 - f) & 2047;
    const int pf = SWZ(posk(f)), pc = SWZ(posk(fc));
    const float ar = re[pf], ai = im[pf];
    const float br = re[pc], bi = im[pc];
    const float qr = 0.5f * (ar + br), qi = 0.5f * (ai - bi);
    const float rr = 0.5f * (ai + bi), ri = -0.5f * (ar - br);
    const float q2 = qr * qr + qi * qi;
    const float r2 = rr * rr + ri * ri;
    const float ph = av * (fatan(0.5f * __logf(q2 + 1e-16f)) - fatan(0.5f * __logf(r2 + 1e-16f)));
    float sp, cp;
    __sincosf(ph, &sp, &cp);
    const float mr = qr * rr + qi * ri;
    const float mi = qi * rr - qr * ri;
    re[pf] = mr * cp - mi * sp;
    im[pf] = mr * sp + mi * cp;
    if (pc != pf) {
      re[pc] = mr * cp + mi * sp;
      im[pc] = mr * sp - mi * cp;
    }
  }
  __syncthreads();

  // ---- inverse stage 4': radix-8, span 1 ----
  {
    const int base = tid << 3;
#pragma unroll
    for (int p = 0; p < 8; p++) { const int ix = SWZ(base + p); zr[p] = re[ix]; zi[p] = im[ix]; }
    idft8(zr, zi);
#pragma unroll
    for (int m = 0; m < 8; m++) { const int ix = SWZ(base + m); re[ix] = zr[m]; im[ix] = zi[m]; }
  }
  __syncthreads();
  // ---- inverse stage 3': conj twiddle then radix-8, span 8 ----
  {
    const int base = ((tid >> 3) << 6) | (tid & 7);
#pragma unroll
    for (int p = 0; p < 8; p++) { const int ix = SWZ(base + (p << 3)); zr[p] = re[ix]; zi[p] = im[ix]; }
    twmul7(zr, zi, c8, -s8);
    idft8(zr, zi);
#pragma unroll
    for (int m = 0; m < 8; m++) { const int ix = SWZ(base + (m << 3)); re[ix] = zr[m]; im[ix] = zi[m]; }
  }
  __syncthreads();
  // ---- inverse stage 2': conj twiddle then radix-8, span 64 ----
  {
    const int base = ((tid >> 6) << 9) | (tid & 63);
#pragma unroll
    for (int p = 0; p < 8; p++) { const int ix = SWZ(base + (p << 6)); zr[p] = re[ix]; zi[p] = im[ix]; }
    twmul7(zr, zi, c64, -s64);
    idft8(zr, zi);
#pragma unroll
    for (int m = 0; m < 8; m++) { const int ix = SWZ(base + (m << 6)); re[ix] = zr[m]; im[ix] = zi[m]; }
  }
  __syncthreads();
  // ---- inverse stage 1': conj twiddle + radix-4, span 512; write real/2048 ----
#pragma unroll
  for (int jj = 0; jj < 2; jj++) {
    const int j = tid + (jj << 8);
    const float x0r = re[SWZ(j)];
    const float x1r = re[SWZ(j + 512)],  x1i = im[SWZ(j + 512)];
    const float x2r = re[SWZ(j + 1024)], x2i = im[SWZ(j + 1024)];
    const float x3r = re[SWZ(j + 1536)], x3i = im[SWZ(j + 1536)];
    const float c1 = w1c[jj], s1 = w1s[jj];
    const float c2 = w2c[jj], s2 = w2s[jj];
    const float c3 = w3c[jj], s3 = w3s[jj];
    const float z1r = x1r * c1 + x1i * s1, z1i = x1i * c1 - x1r * s1;
    const float z2r = x2r * c2 + x2i * s2;
    const float z3r = x3r * c3 + x3i * s3, z3i = x3i * c3 - x3r * s3;
    const float ar = x0r + z2r;
    const float br = x0r - z2r;
    const float cr = z1r + z3r;
    const float di = z1i - z3i;
    q[j]        = (ar + cr) * (1.0f / 2048.0f);
    q[j + 512]  = (br - di) * (1.0f / 2048.0f);
    q[j + 1024] = (ar - cr) * (1.0f / 2048.0f);
    q[j + 1536] = (br + di) * (1.0f / 2048.0f);
  }
}

// ---------- fused transpose + hamilton + sp_ln + gate + rot + residual + out_ln + quant ----
// VECTORIZED ownership: thread owns d = c2*256 + lane*4 + e (e=0..3) -> all global/LDS
// accesses are float4/char4. Hamilton/rot/LN are elementwise in e; LN sums unchanged.
__global__ __launch_bounds__(256) void fused2q_k(const float* __restrict__ inter,  // (CHB, D, T)
                                                 const float* __restrict__ Hb,     // (chm, D)
                                                 const float* __restrict__ spw, const float* __restrict__ spb,
                                                 const float* __restrict__ gate, const float* __restrict__ rot,
                                                 const float* __restrict__ ow, const float* __restrict__ ob,
                                                 I8* __restrict__ xh8, I8* __restrict__ xl8,
                                                 float* __restrict__ sxc) {
  __shared__ float ti[8 * 1028];   // 8 rows, +4 pad per row (4112B stride, 16B aligned)
  const int tid = threadIdx.x;
  const int m0 = blockIdx.x * 8;
  const int lb = m0 >> 11;
  const int t0 = m0 & (T_ - 1);
  // ---- stage 8t x 1024n tile: float4 along t ----
  {
    const int tq = (tid & 1) * 4;
    const int nb = tid >> 1;
#pragma unroll
    for (int p = 0; p < 8; p++) {
      const int n = p * 128 + nb;
      const float4 v = *(const float4*)(inter + ((size_t)((lb << 10) | n)) * T_ + t0 + tq);
      ti[(tq + 0) * 1028 + n] = fixf(v.x);
      ti[(tq + 1) * 1028 + n] = fixf(v.y);
      ti[(tq + 2) * 1028 + n] = fixf(v.z);
      ti[(tq + 3) * 1028 + n] = fixf(v.w);
    }
  }
  __syncthreads();
  const int wv = tid >> 6, lane = tid & 63;
  float rr_[16];
#pragma unroll
  for (int i = 0; i < 16; i++) rr_[i] = rot[i];
  const int dl = lane * 4;                 // d_low base: 4 consecutive features mod 256
  const f32x4 g4 = *(const f32x4*)(gate + dl);
#pragma unroll
  for (int rwi = 0; rwi < 2; rwi++) {
    const int tt = wv * 2 + rwi;
    const int m = m0 + tt;
    const size_t mb = (size_t)m * D_;
    const float sxold = sxc[m];
    f32x4 iv[4], hv[4];
#pragma unroll
    for (int c2 = 0; c2 < 4; c2++) {
      iv[c2] = *(const f32x4*)(ti + tt * 1028 + c2 * 256 + dl);
      f32x4 h = *(const f32x4*)(Hb + mb + c2 * 256 + dl);
#pragma unroll
      for (int e = 0; e < 4; e++) h[e] = fixf(h[e]);
      hv[c2] = h;
    }
    f32x4 o[4];
    o[0] = iv[0] * hv[0] - iv[1] * hv[1] - iv[2] * hv[2] - iv[3] * hv[3];
    o[1] = iv[0] * hv[1] + iv[1] * hv[0] + iv[2] * hv[3] - iv[3] * hv[2];
    o[2] = iv[0] * hv[2] - iv[1] * hv[3] + iv[2] * hv[0] + iv[3] * hv[1];
    o[3] = iv[0] * hv[3] + iv[1] * hv[2] - iv[2] * hv[1] + iv[3] * hv[0];
    float s = 0.f, ss = 0.f;
#pragma unroll
    for (int c2 = 0; c2 < 4; c2++)
#pragma unroll
      for (int e = 0; e < 4; e++) { const float x = o[c2][e]; s += x; ss += x * x; }
#pragma unroll
    for (int off = 32; off > 0; off >>= 1) { s += __shfl_xor(s, off); ss += __shfl_xor(ss, off); }
    const float mean = s * (1.0f / 1024.0f);
    const float rstd = rsqrtf(ss * (1.0f / 1024.0f) - mean * mean + 1e-5f);
    f32x4 xf[4];
#pragma unroll
    for (int c2 = 0; c2 < 4; c2++) {
      const f32x4 w4 = *(const f32x4*)(spw + c2 * 256 + dl);
      const f32x4 b4 = *(const f32x4*)(spb + c2 * 256 + dl);
      xf[c2] = ((o[c2] - mean) * rstd * w4 + b4) * g4;
    }
    f32x4 y[4];
#pragma unroll
    for (int j = 0; j < 4; j++) {
      f32x4 a = rr_[j * 4 + 0] * xf[0] + rr_[j * 4 + 1] * xf[1]
              + rr_[j * 4 + 2] * xf[2] + rr_[j * 4 + 3] * xf[3];
      const char4 h4 = *(const char4*)(xh8 + mb + j * 256 + dl);
      const char4 l4 = *(const char4*)(xl8 + mb + j * 256 + dl);
      f32x4 res;
      res[0] = sxold * ((float)h4.x + (float)l4.x * (1.f / 256.f));
      res[1] = sxold * ((float)h4.y + (float)l4.y * (1.f / 256.f));
      res[2] = sxold * ((float)h4.z + (float)l4.z * (1.f / 256.f));
      res[3] = sxold * ((float)h4.w + (float)l4.w * (1.f / 256.f));
      y[j] = a + res;
    }
    float s2 = 0.f, ss2 = 0.f;
#pragma unroll
    for (int j = 0; j < 4; j++)
#pragma unroll
      for (int e = 0; e < 4; e++) { const float x = y[j][e]; s2 += x; ss2 += x * x; }
#pragma unroll
    for (int off = 32; off > 0; off >>= 1) { s2 += __shfl_xor(s2, off); ss2 += __shfl_xor(ss2, off); }
    const float mean2 = s2 * (1.0f / 1024.0f);
    const float rstd2 = rsqrtf(ss2 * (1.0f / 1024.0f) - mean2 * mean2 + 1e-5f);
    f32x4 vout[4];
    float mx = 0.f;
#pragma unroll
    for (int j = 0; j < 4; j++) {
      const f32x4 w4 = *(const f32x4*)(ow + j * 256 + dl);
      const f32x4 b4 = *(const f32x4*)(ob + j * 256 + dl);
      const f32x4 v = (y[j] - mean2) * rstd2 * w4 + b4;
      vout[j] = v;
#pragma unroll
      for (int e = 0; e < 4; e++) mx = fmaxf(mx, fabsf(v[e]));
    }
#pragma unroll
    for (int off = 32; off > 0; off >>= 1) mx = fmaxf(mx, __shfl_xor(mx, off));
    const float mxg = fmaxf(mx, 1e-30f);
    const float sxn = mxg * (1.f / 127.f);
    const float inv = 127.f / mxg;
    if (lane == 0) sxc[m] = sxn;
#pragma unroll
    for (int j = 0; j < 4; j++) {
      char4 ho, lo2;
      int qh, ql;
      quant2(vout[j][0], inv, qh, ql); ho.x = (I8)qh; lo2.x = (I8)ql;
      quant2(vout[j][1], inv, qh, ql); ho.y = (I8)qh; lo2.y = (I8)ql;
      quant2(vout[j][2], inv, qh, ql); ho.z = (I8)qh; lo2.z = (I8)ql;
      quant2(vout[j][3], inv, qh, ql); ho.w = (I8)qh; lo2.w = (I8)ql;
      *(char4*)(xh8 + mb + j * 256 + dl) = ho;
      *(char4*)(xl8 + mb + j * 256 + dl) = lo2;
    }
  }
}

// ---------- mean over T (partials + atomics; pooled must be zeroed) ----------
__global__ __launch_bounds__(256) void poolq_k(const I8* __restrict__ xh, const I8* __restrict__ xl,
                                               const float* __restrict__ sx,
                                               float* __restrict__ pooled) {
  const int b = blockIdx.z;
  const int d = blockIdx.x * 256 + threadIdx.x;
  const int t0 = blockIdx.y * 256;
  float s = 0.f;
  for (int t = t0; t < t0 + 256; t++) {
    const int row = b * T_ + t;
    const size_t idx = (size_t)row * D_ + d;
    s += sx[row] * ((float)xh[idx] + (float)xl[idx] * (1.f / 256.f));
  }
  atomicAdd(&pooled[b * D_ + d], s);
}

// ---------- classifier LN ----------
__global__ __launch_bounds__(256) void clsln_k(const float* __restrict__ pooled, const float* __restrict__ w,
                                               const float* __restrict__ bias, float* __restrict__ h) {
  __shared__ float red[8];
  const int b = blockIdx.x;
  const int d = threadIdx.x;
  float v[4];
#pragma unroll
  for (int j = 0; j < 4; j++) v[j] = fixf(pooled[b * D_ + j * 256 + d]) * (1.0f / (float)T_);
  float s = v[0] + v[1] + v[2] + v[3];
  float ss = v[0] * v[0] + v[1] * v[1] + v[2] * v[2] + v[3] * v[3];
  breduce2(s, ss, red);
  const float mean = s * (1.0f / (float)D_);
  const float rstd = rsqrtf(ss * (1.0f / (float)D_) - mean * mean + 1e-5f);
#pragma unroll
  for (int j = 0; j < 4; j++)
    h[b * D_ + j * 256 + d] = (v[j] - mean) * rstd * w[j * 256 + d] + bias[j * 256 + d];
}

// ---------- classifier GEMM: one wave per (b, n) ----------
__global__ __launch_bounds__(256) void cls_k(const float* __restrict__ h, const float* __restrict__ W,
                                             const float* __restrict__ cb, float* __restrict__ out) {
  const int wv = blockIdx.x * 4 + (threadIdx.x >> 6);
  const int lane = threadIdx.x & 63;
  const int b = wv / NCLS_;
  const int n = wv - b * NCLS_;
  const float* hb = h + b * D_;
  const float* wr = W + (size_t)n * D_;
  float s = 0.f;
  for (int j = lane; j < D_; j += 64) s += hb[j] * wr[j];
#pragma unroll
  for (int off = 32; off > 0; off >>= 1) s += __shfl_down(s, off);
  if (lane == 0) out[b * NCLS_ + n] = fixf(s + cb[n]);
}

// ---------- launch ----------
extern "C" void kernel_launch(void* const* d_in, const int* in_sizes, int n_in,
                              void* d_out, int out_size, void* d_ws, size_t ws_size,
                              hipStream_t stream) {
  (void)in_sizes; (void)n_in; (void)out_size;
  const int* tokens = (const int*)d_in[0];
  const float* emb = (const float*)d_in[1];
  const float* pos = (const float*)d_in[2];
  const float* Wq = (const float*)d_in[3];
  const float* bq = (const float*)d_in[4];
  const float* Wr = (const float*)d_in[5];
  const float* br = (const float*)d_in[6];
  const float* Wh = (const float*)d_in[7];
  const float* bh = (const float*)d_in[8];
  const float* alpha = (const float*)d_in[9];
  const float* spw = (const float*)d_in[10];
  const float* spb = (const float*)d_in[11];
  const float* gate = (const float*)d_in[12];
  const float* rot = (const float*)d_in[13];
  const float* outw = (const float*)d_in[14];
  const float* outb = (const float*)d_in[15];
  const float* clw = (const float*)d_in[16];
  const float* clb = (const float*)d_in[17];
  const float* clsW = (const float*)d_in[18];
  const float* clsb = (const float*)d_in[19];
  float* out = (float*)d_out;

  // ---- adaptive footprint from ws_size ----
  const size_t MB = 1048576;
  int CHB;
  if      (ws_size >= 136 * MB) CHB = 4;
  else if (ws_size >=  88 * MB) CHB = 2;
  else                          CHB = 1;
  const int nchunks = B_ / CHB;
  const int chm = CHB * T_;
  const size_t chunkf = (size_t)CHB * T_ * D_ * 4;

  char* ws = (char*)d_ws;
  I8* xh8 = (I8*)ws;                       // 16 MB
  I8* xl8 = (I8*)(ws + 16 * MB);           // 16 MB
  I8* Wh8 = (I8*)(ws + 32 * MB);           // 3 MB (Q,R,H)
  I8* Wl8 = (I8*)(ws + 35 * MB);           // 3 MB
  float* sx = (float*)(ws + 38 * MB);      // 64 KB (per-row x scales)
  float* sw = (float*)(ws + 38 * MB + 65536);  // 12 KB (per-row W scales, 3 secs)
  char* fb = ws + 39 * MB;
  float* QTc = (float*)fb;
  float* RTc = (float*)(fb + chunkf);
  float* Hc  = (float*)(fb + 2 * chunkf);
  float* pooled = (float*)fb;              // reuse after layers
  float* hbuf   = (float*)(fb + 32768);

  embedq_k<<<M_, 256, 0, stream>>>(tokens, emb, pos, xh8, xl8, sx);

  const dim3 gemm_grid(24, chm / 128);
  for (int l = 0; l < L_; l++) {
    const size_t wo = (size_t)l * DD_;
    wsplitq_k<<<3072, 256, 0, stream>>>(Wq + wo, Wr + wo, Wh + wo, Wh8, Wl8, sw);
    for (int c = 0; c < nchunks; c++) {
      const size_t xoff = (size_t)c * chm * D_;
      gemm3q_k<<<gemm_grid, 256, 0, stream>>>(xh8 + xoff, xl8 + xoff, Wh8, Wl8,
                                              sx + (size_t)c * chm, sw,
                                              bq + l * D_, br + l * D_, bh + l * D_,
                                              QTc, RTc, Hc);
      fft_spectral_k<<<CHB * D_, 256, 0, stream>>>(QTc, RTc, alpha + l * QD_);
      fused2q_k<<<chm / 8, 256, 0, stream>>>(QTc, Hc, spw + l * D_, spb + l * D_,
                                             gate + l * QD_, rot + l * 16,
                                             outw + l * D_, outb + l * D_,
                                             xh8 + xoff, xl8 + xoff, sx + (size_t)c * chm);
    }
  }

  hipMemsetAsync(pooled, 0, B_ * D_ * sizeof(float), stream);
  poolq_k<<<dim3(4, 8, 8), 256, 0, stream>>>(xh8, xl8, sx, pooled);
  clsln_k<<<B_, 256, 0, stream>>>(pooled, clw, clb, hbuf);
  cls_k<<<(B_ * NCLS_) / 4, 256, 0, stream>>>(hbuf, clsW, clsb, out);
}

// Round 15
// 1614.815 us; speedup vs baseline: 1.1215x; 1.1142x over previous
//
#include <hip/hip_runtime.h>

typedef signed char I8;
typedef __attribute__((ext_vector_type(4))) int i32x4;
typedef __attribute__((ext_vector_type(4))) float f32x4;

#define B_   8
#define T_   2048
#define D_   1024
#define QD_  256
#define L_   4
#define M_   (B_ * T_)      // 16384
#define NCLS_ 1000
#define DD_  (D_ * D_)

// ---------- helpers ----------
__device__ __forceinline__ float fixf(float v) {
  unsigned u = __float_as_uint(v);
  return ((u & 0x7F800000u) == 0x7F800000u) ? 0.f : v;
}
__device__ __forceinline__ void glds16(const void* g, void* l) {
  __builtin_amdgcn_global_load_lds((const __attribute__((address_space(1))) void*)g,
                                   (__attribute__((address_space(3))) void*)l, 16, 0, 0);
}
__device__ __forceinline__ int clampi(int q) { return q < -128 ? -128 : (q > 127 ? 127 : q); }
// quantize v (|v| <= 127/inv) to 16-bit fixed point: v ~= (qh + ql/256)/inv
__device__ __forceinline__ void quant2(float v, float inv, int& qh, int& ql) {
  const float t = v * inv;
  int h = clampi((int)rintf(t));
  const float r = t - (float)h;
  int l = clampi((int)rintf(r * 256.f));
  qh = h; ql = l;
}
// fast atan: 4-term minimax on [0,1] + reciprocal fold; |err| <= ~1e-4 rad
__device__ __forceinline__ float fatan(float x) {
  const float ax = fabsf(x);
  const bool big = ax > 1.f;
  const float z = big ? 1.f / ax : ax;
  const float z2 = z * z;
  const float p = z * (0.99986f + z2 * (-0.33030f + z2 * (0.18014f + z2 * (-0.085133f))));
  const float r = big ? 1.57079632679f - p : p;
  return copysignf(r, x);
}
// block=256 (4 waves): reduce two sums across block
__device__ __forceinline__ void breduce2(float& a, float& b, float* buf) {
#pragma unroll
  for (int off = 32; off > 0; off >>= 1) { a += __shfl_down(a, off); b += __shfl_down(b, off); }
  const int lane = threadIdx.x & 63, w = threadIdx.x >> 6;
  __syncthreads();
  if (lane == 0) { buf[w] = a; buf[4 + w] = b; }
  __syncthreads();
  a = buf[0] + buf[1] + buf[2] + buf[3];
  b = buf[4] + buf[5] + buf[6] + buf[7];
}
// block=256: max across block
__device__ __forceinline__ float bmaxall(float a, float* buf) {
#pragma unroll
  for (int off = 32; off > 0; off >>= 1) a = fmaxf(a, __shfl_down(a, off));
  const int lane = threadIdx.x & 63, w = threadIdx.x >> 6;
  __syncthreads();
  if (lane == 0) buf[w] = a;
  __syncthreads();
  return fmaxf(fmaxf(buf[0], buf[1]), fmaxf(buf[2], buf[3]));
}

// ---------- weight quant: ALL LAYERS in one dispatch ----------
// grid.x = L*3*1024; per block: one row of one (layer, sec) matrix.
__global__ __launch_bounds__(256) void wsplitq_k(const float* __restrict__ Wq,
                                                 const float* __restrict__ Wr,
                                                 const float* __restrict__ Wh,
                                                 I8* __restrict__ hi, I8* __restrict__ lo,
                                                 float* __restrict__ sw) {
  __shared__ float red[4];
  const int bi = blockIdx.x;
  const int l = bi >> 12;                  // 4096 blocks per layer (3*1024 rounded? no: exact 3072)
  // NOTE: use exact decomposition for 3072 blocks/layer:
  const int l2 = bi / 3072;
  const int rem = bi - l2 * 3072;
  const int sec = rem >> 10;
  const int n = rem & 1023;
  (void)l;
  const float* wbase = (sec == 0) ? Wq : (sec == 1) ? Wr : Wh;
  const float* w = wbase + (size_t)l2 * DD_;
  const int c = threadIdx.x * 4;
  const float4 v = *(const float4*)(w + (size_t)n * D_ + c);
  const float vv[4] = {v.x, v.y, v.z, v.w};
  float mx = fmaxf(fmaxf(fabsf(v.x), fabsf(v.y)), fmaxf(fabsf(v.z), fabsf(v.w)));
  mx = bmaxall(mx, red);
  const float s = fmaxf(mx, 1e-30f) * (1.f / 127.f);
  const int mat = l2 * 3 + sec;
  if (threadIdx.x == 0) sw[mat * D_ + n] = s;
  const float inv = 127.f / fmaxf(mx, 1e-30f);
  unsigned ph = 0, pl = 0;
#pragma unroll
  for (int j = 0; j < 4; j++) {
    int qh, ql;
    quant2(vv[j], inv, qh, ql);
    ph |= ((unsigned)(unsigned char)(I8)qh) << (8 * j);
    pl |= ((unsigned)(unsigned char)(I8)ql) << (8 * j);
  }
  const size_t o = (size_t)mat * DD_ + (size_t)n * D_ + c;
  *(unsigned*)(hi + o) = ph;
  *(unsigned*)(lo + o) = pl;
}

// ---------- embed: x = embed[tokens] + pos -> i8 hi/lo planes + per-row scale ----------
__global__ __launch_bounds__(256) void embedq_k(const int* __restrict__ tok,
                                                const float* __restrict__ emb,
                                                const float* __restrict__ pos,
                                                I8* __restrict__ xh, I8* __restrict__ xl,
                                                float* __restrict__ sx) {
  __shared__ float red[4];
  const int m = blockIdx.x;
  const int t = m & (T_ - 1);
  const int tk = tok[m];
  const int c = threadIdx.x * 4;
  const float* e = emb + (size_t)tk * D_ + c;
  const float* p = pos + (size_t)t * D_ + c;
  float v[4];
  float mx = 0.f;
#pragma unroll
  for (int i = 0; i < 4; i++) { v[i] = e[i] + p[i]; mx = fmaxf(mx, fabsf(v[i])); }
  mx = bmaxall(mx, red);
  const float s = fmaxf(mx, 1e-30f) * (1.f / 127.f);
  if (threadIdx.x == 0) sx[m] = s;
  const float inv = 127.f / fmaxf(mx, 1e-30f);
  unsigned ph = 0, pl = 0;
#pragma unroll
  for (int i = 0; i < 4; i++) {
    int qh, ql;
    quant2(v[i], inv, qh, ql);
    ph |= ((unsigned)(unsigned char)(I8)qh) << (8 * i);
    pl |= ((unsigned)(unsigned char)(I8)ql) << (8 * i);
  }
  const size_t o = (size_t)m * D_ + c;
  *(unsigned*)(xh + o) = ph;
  *(unsigned*)(xl + o) = pl;
}

// ---------- GEMM (i8 fixed-point): C = sx[m]*sw[n]*(hh + cross/256) + bias, Q+R+H fused ----
// 128x128 tile, BK=64 i8, 4 waves of 64x64, mfma_i32_16x16x64_i8.
// Double-buffered LDS + counted vmcnt(8).
// grid.x = 24: 0-7 -> Q (TR), 8-15 -> R (TR), 16-23 -> H (natural).
__global__ __launch_bounds__(256, 2) void gemm3q_k(const I8* __restrict__ Ahi,
                                                   const I8* __restrict__ Alo,
                                                   const I8* __restrict__ Whi,
                                                   const I8* __restrict__ Wlo,
                                                   const float* __restrict__ sx,
                                                   const float* __restrict__ sw,
                                                   const float* __restrict__ bq,
                                                   const float* __restrict__ br,
                                                   const float* __restrict__ bh,
                                                   float* __restrict__ outQ,
                                                   float* __restrict__ outR,
                                                   float* __restrict__ outH) {
  __shared__ __align__(16) I8 lds[65536];  // 2 buffers x 32KB
  char* sbase = (char*)lds;
  const int tid = threadIdx.x;
  const int lane = tid & 63;
  const int wave = tid >> 6;
  const int wr = wave >> 1, wc = wave & 1;
  const int sec = blockIdx.x >> 3;
  const int n0 = (blockIdx.x & 7) * 128;
  const int m0 = blockIdx.y * 128;
  const I8* Bhi = Whi + (size_t)sec * DD_;
  const I8* Blo = Wlo + (size_t)sec * DD_;
  const float* bias = (sec == 0) ? bq : (sec == 1) ? br : bh;
  float* out = (sec == 0) ? outQ : (sec == 1) ? outR : outH;
  const bool TR = sec < 2;

  i32x4 aHH[4][4], aX[4][4];
#pragma unroll
  for (int i = 0; i < 4; i++)
#pragma unroll
    for (int j = 0; j < 4; j++) { aHH[i][j] = (i32x4){0, 0, 0, 0}; aX[i][j] = (i32x4){0, 0, 0, 0}; }

  const int lrow = tid >> 2;            // 0..63
  const int lcolb = (tid & 3) * 16;     // bytes within 64B k-row
  const char* gah = (const char*)Ahi + (size_t)(m0 + lrow) * D_ + lcolb;
  const char* gal = (const char*)Alo + (size_t)(m0 + lrow) * D_ + lcolb;
  const char* gbh = (const char*)Bhi + (size_t)(n0 + lrow) * D_ + lcolb;
  const char* gbl = (const char*)Blo + (size_t)(n0 + lrow) * D_ + lcolb;

  const int koff = (lane >> 4) * 16;                 // byte k-offset of fragment
  const int mA = (wr * 64 + (lane & 15)) * 64;       // byte row base (A)
  const int nB = (wc * 64 + (lane & 15)) * 64;       // byte row base (B)

  // ---- prologue: stage K-tile 0 into buffer 0, drain fully ----
  {
    char* d = sbase + tid * 16;
    glds16(gah, d);
    glds16(gah + 64 * D_, d + 4096);
    glds16(gal, d + 8192);
    glds16(gal + 64 * D_, d + 12288);
    glds16(gbh, d + 16384);
    glds16(gbh + 64 * D_, d + 20480);
    glds16(gbl, d + 24576);
    glds16(gbl + 64 * D_, d + 28672);
    gah += 64; gal += 64; gbh += 64; gbl += 64;
  }
  asm volatile("s_waitcnt vmcnt(0)" ::: "memory");
  __builtin_amdgcn_s_barrier();

  int cur = 0;
  for (int kk = 0; kk < 1024; kk += 64) {
    if (kk < 1024 - 64) {
      char* d = sbase + (cur ^ 1) * 32768 + tid * 16;
      glds16(gah, d);
      glds16(gah + 64 * D_, d + 4096);
      glds16(gal, d + 8192);
      glds16(gal + 64 * D_, d + 12288);
      glds16(gbh, d + 16384);
      glds16(gbh + 64 * D_, d + 20480);
      glds16(gbl, d + 24576);
      glds16(gbl + 64 * D_, d + 28672);
      gah += 64; gal += 64; gbh += 64; gbl += 64;
      asm volatile("s_waitcnt vmcnt(8)" ::: "memory");
    } else {
      asm volatile("s_waitcnt vmcnt(0)" ::: "memory");
    }
    __builtin_amdgcn_s_barrier();
    const char* sb = sbase + cur * 32768;
    i32x4 ah[4], al[4], bh2[4], bl2[4];
#pragma unroll
    for (int i = 0; i < 4; i++) {
      const char* pa = sb + mA + i * 1024 + koff;
      ah[i] = *(const i32x4*)pa;
      al[i] = *(const i32x4*)(pa + 8192);
    }
#pragma unroll
    for (int j = 0; j < 4; j++) {
      const char* pb = sb + 16384 + nB + j * 1024 + koff;
      bh2[j] = *(const i32x4*)pb;
      bl2[j] = *(const i32x4*)(pb + 8192);
    }
#pragma unroll
    for (int i = 0; i < 4; i++)
#pragma unroll
      for (int j = 0; j < 4; j++) {
        aHH[i][j] = __builtin_amdgcn_mfma_i32_16x16x64_i8(ah[i], bh2[j], aHH[i][j], 0, 0, 0);
        aX[i][j]  = __builtin_amdgcn_mfma_i32_16x16x64_i8(ah[i], bl2[j], aX[i][j], 0, 0, 0);
        aX[i][j]  = __builtin_amdgcn_mfma_i32_16x16x64_i8(al[i], bh2[j], aX[i][j], 0, 0, 0);
      }
    __builtin_amdgcn_s_barrier();
    cur ^= 1;
  }

#pragma unroll
  for (int j = 0; j < 4; j++) {
    const int n = n0 + wc * 64 + j * 16 + (lane & 15);
    const float swv = sw[sec * D_ + n];
    const float bv = bias[n];
#pragma unroll
    for (int i = 0; i < 4; i++) {
      const int mb = m0 + wr * 64 + i * 16 + ((lane >> 4) << 2);
      const float4 sx4 = *(const float4*)(sx + mb);
      const float sxa[4] = {sx4.x, sx4.y, sx4.z, sx4.w};
#pragma unroll
      for (int r = 0; r < 4; r++) {
        const int m = mb + r;                  // chunk-local row
        const float v = sxa[r] * swv * ((float)aHH[i][j][r] + (float)aX[i][j][r] * (1.f / 256.f)) + bv;
        if (TR) {
          const int lb = m >> 11, t = m & (T_ - 1);  // local batch, time
          out[(((size_t)lb << 10) + n) * T_ + t] = v;
        } else {
          out[(size_t)m * D_ + n] = v;
        }
      }
    }
  }
}

// ================= register-blocked FFT (radix [4,8,8,8]) =================
__device__ __forceinline__ int SWZ(int a) { return a ^ ((a >> 5) & 31); }
__device__ __forceinline__ int posk(int k) {
  return ((k & 3) << 9) | (((k >> 2) & 7) << 6) | (((k >> 5) & 7) << 3) | (k >> 8);
}

// forward 8-pt DFT (omega = e^{-2pi i/8})
__device__ __forceinline__ void dft8f(float* zr, float* zi) {
  const float C = 0.70710678118654752f;
  float sr = zr[0] + zr[4], si = zi[0] + zi[4];
  float tr = zr[0] - zr[4], ti = zi[0] - zi[4];
  float ur = zr[2] + zr[6], ui = zi[2] + zi[6];
  float vr = zr[2] - zr[6], vi = zi[2] - zi[6];
  const float e0r = sr + ur, e0i = si + ui;
  const float e2r = sr - ur, e2i = si - ui;
  const float e1r = tr + vi, e1i = ti - vr;
  const float e3r = tr - vi, e3i = ti + vr;
  sr = zr[1] + zr[5]; si = zi[1] + zi[5];
  tr = zr[1] - zr[5]; ti = zi[1] - zi[5];
  ur = zr[3] + zr[7]; ui = zi[3] + zi[7];
  vr = zr[3] - zr[7]; vi = zi[3] - zi[7];
  const float o0r = sr + ur, o0i = si + ui;
  const float o2r = sr - ur, o2i = si - ui;
  const float o1r = tr + vi, o1i = ti - vr;
  const float o3r = tr - vi, o3i = ti + vr;
  const float w1r = C * (o1r + o1i), w1i = C * (o1i - o1r);
  const float w2r = o2i,             w2i = -o2r;
  const float w3r = C * (o3i - o3r), w3i = -C * (o3r + o3i);
  zr[0] = e0r + o0r; zi[0] = e0i + o0i;
  zr[4] = e0r - o0r; zi[4] = e0i - o0i;
  zr[1] = e1r + w1r; zi[1] = e1i + w1i;
  zr[5] = e1r - w1r; zi[5] = e1i - w1i;
  zr[2] = e2r + w2r; zi[2] = e2i + w2i;
  zr[6] = e2r - w2r; zi[6] = e2i - w2i;
  zr[3] = e3r + w3r; zi[3] = e3i + w3i;
  zr[7] = e3r - w3r; zi[7] = e3i - w3i;
}

// inverse (unscaled) 8-pt DFT (omega = e^{+2pi i/8})
__device__ __forceinline__ void idft8(float* zr, float* zi) {
  const float C = 0.70710678118654752f;
  float sr = zr[0] + zr[4], si = zi[0] + zi[4];
  float tr = zr[0] - zr[4], ti = zi[0] - zi[4];
  float ur = zr[2] + zr[6], ui = zi[2] + zi[6];
  float vr = zr[2] - zr[6], vi = zi[2] - zi[6];
  const float e0r = sr + ur, e0i = si + ui;
  const float e2r = sr - ur, e2i = si - ui;
  const float e1r = tr - vi, e1i = ti + vr;
  const float e3r = tr + vi, e3i = ti - vr;
  sr = zr[1] + zr[5]; si = zi[1] + zi[5];
  tr = zr[1] - zr[5]; ti = zi[1] - zi[5];
  ur = zr[3] + zr[7]; ui = zi[3] + zi[7];
  vr = zr[3] - zr[7]; vi = zi[3] - zi[7];
  const float o0r = sr + ur, o0i = si + ui;
  const float o2r = sr - ur, o2i = si - ui;
  const float o1r = tr - vi, o1i = ti + vr;
  const float o3r = tr + vi, o3i = ti - vr;
  const float w1r = C * (o1r - o1i), w1i = C * (o1r + o1i);
  const float w2r = -o2i,            w2i = o2r;
  const float w3r = -C * (o3r + o3i), w3i = C * (o3r - o3i);
  zr[0] = e0r + o0r; zi[0] = e0i + o0i;
  zr[4] = e0r - o0r; zi[4] = e0i - o0i;
  zr[1] = e1r + w1r; zi[1] = e1i + w1i;
  zr[5] = e1r - w1r; zi[5] = e1i - w1i;
  zr[2] = e2r + w2r; zi[2] = e2i + w2i;
  zr[6] = e2r - w2r; zi[6] = e2i - w2i;
  zr[3] = e3r + w3r; zi[3] = e3i + w3i;
  zr[7] = e3r - w3r; zi[7] = e3i - w3i;
}

// z[m] *= w^m for m=1..7
__device__ __forceinline__ void twmul7(float* zr, float* zi, float wc, float ws) {
  float cr = wc, ci = ws;
#pragma unroll
  for (int m = 1; m < 8; m++) {
    const float t = zr[m] * cr - zi[m] * ci;
    zi[m] = zr[m] * ci + zi[m] * cr;
    zr[m] = t;
    if (m < 7) { const float nr = cr * wc - ci * ws; ci = cr * ws + ci * wc; cr = nr; }
  }
}

// ---------- fused FFT + spectral filter + IFFT ----------
__global__ __launch_bounds__(256) void fft_spectral_k(float* __restrict__ QT,
                                                      const float* __restrict__ RT,
                                                      const float* __restrict__ alpha) {
  __shared__ float re[2048], im[2048];   // 16KB, swizzled slots
  const int tid = threadIdx.x;
  const int seq = blockIdx.x;  // lb*D + n
  const float av = alpha[seq & (QD_ - 1)];
  float* q = QT + (size_t)seq * T_;
  const float* r = RT + (size_t)seq * T_;
  const float NTPI = -6.28318530717958647692f;

  float w1c[2], w1s[2], w2c[2], w2s[2], w3c[2], w3s[2];
  float c64, s64, c8, s8;

  // ---- forward stage 1: radix-4 DIF, span 512 ----
#pragma unroll
  for (int jj = 0; jj < 2; jj++) {
    const int j = tid + (jj << 8);
    const float x0r = q[j],        x0i = r[j];
    const float x1r = q[j + 512],  x1i = r[j + 512];
    const float x2r = q[j + 1024], x2i = r[j + 1024];
    const float x3r = q[j + 1536], x3i = r[j + 1536];
    float ws, wcs;
    __sincosf(NTPI * (float)j * (1.0f / 2048.0f), &ws, &wcs);
    const float w2r = wcs * wcs - ws * ws, w2i = 2.0f * wcs * ws;
    const float w3r = wcs * w2r - ws * w2i, w3i = wcs * w2i + ws * w2r;
    w1c[jj] = wcs; w1s[jj] = ws; w2c[jj] = w2r; w2s[jj] = w2i; w3c[jj] = w3r; w3s[jj] = w3i;
    const float ar = x0r + x2r, ai = x0i + x2i;
    const float br = x0r - x2r, bi = x0i - x2i;
    const float cr = x1r + x3r, ci = x1i + x3i;
    const float dr = x1r - x3r, di = x1i - x3i;
    re[SWZ(j)] = ar + cr;  im[SWZ(j)] = ai + ci;
    const float g1r = br + di, g1i = bi - dr;
    re[SWZ(j + 512)] = g1r * wcs - g1i * ws;   im[SWZ(j + 512)] = g1r * ws + g1i * wcs;
    const float g2r = ar - cr, g2i = ai - ci;
    re[SWZ(j + 1024)] = g2r * w2r - g2i * w2i; im[SWZ(j + 1024)] = g2r * w2i + g2i * w2r;
    const float g3r = br - di, g3i = bi + dr;
    re[SWZ(j + 1536)] = g3r * w3r - g3i * w3i; im[SWZ(j + 1536)] = g3r * w3i + g3i * w3r;
  }
  __syncthreads();

  float zr[8], zi[8];
  // ---- forward stage 2: radix-8, span 64 ----
  {
    const int base = ((tid >> 6) << 9) | (tid & 63);
#pragma unroll
    for (int p = 0; p < 8; p++) { const int ix = SWZ(base + (p << 6)); zr[p] = re[ix]; zi[p] = im[ix]; }
    dft8f(zr, zi);
    __sincosf(NTPI * (float)(tid & 63) * (1.0f / 512.0f), &s64, &c64);
    twmul7(zr, zi, c64, s64);
#pragma unroll
    for (int m = 0; m < 8; m++) { const int ix = SWZ(base + (m << 6)); re[ix] = zr[m]; im[ix] = zi[m]; }
  }
  __syncthreads();
  // ---- forward stage 3: radix-8, span 8 ----
  {
    const int base = ((tid >> 3) << 6) | (tid & 7);
#pragma unroll
    for (int p = 0; p < 8; p++) { const int ix = SWZ(base + (p << 3)); zr[p] = re[ix]; zi[p] = im[ix]; }
    dft8f(zr, zi);
    __sincosf(NTPI * (float)(tid & 7) * (1.0f / 64.0f), &s8, &c8);
    twmul7(zr, zi, c8, s8);
#pragma unroll
    for (int m = 0; m < 8; m++) { const int ix = SWZ(base + (m << 3)); re[ix] = zr[m]; im[ix] = zi[m]; }
  }
  __syncthreads();
  // ---- forward stage 4: radix-8, span 1 ----
  {
    const int base = tid << 3;
#pragma unroll
    for (int p = 0; p < 8; p++) { const int ix = SWZ(base + p); zr[p] = re[ix]; zi[p] = im[ix]; }
    dft8f(zr, zi);
#pragma unroll
    for (int m = 0; m < 8; m++) { const int ix = SWZ(base + m); re[ix] = zr[m]; im[ix] = zi[m]; }
  }
  __syncthreads();

  // ---- spectral filter in digit-reversed domain ----
  for (int f = tid; f <= 1024; f += 256) {
    const int fc = (2048 - f) & 2047;
    const int pf = SWZ(posk(f)), pc = SWZ(posk(fc));
    const float ar = re[pf], ai = im[pf];
    const float br = re[pc], bi = im[pc];
    const float qr = 0.5f * (ar + br), qi = 0.5f * (ai - bi);
    const float rr = 0.5f * (ai + bi), ri = -0.5f * (ar - br);
    const float q2 = qr * qr + qi * qi;
    const float r2 = rr * rr + ri * ri;
    const float ph = av * (fatan(0.5f * __logf(q2 + 1e-16f)) - fatan(0.5f * __logf(r2 + 1e-16f)));
    float sp, cp;
    __sincosf(ph, &sp, &cp);
    const float mr = qr * rr + qi * ri;
    const float mi = qi * rr - qr * ri;
    re[pf] = mr * cp - mi * sp;
    im[pf] = mr * sp + mi * cp;
    if (pc != pf) {
      re[pc] = mr * cp + mi * sp;
      im[pc] = mr * sp - mi * cp;
    }
  }
  __syncthreads();

  // ---- inverse stage 4': radix-8, span 1 ----
  {
    const int base = tid << 3;
#pragma unroll
    for (int p = 0; p < 8; p++) { const int ix = SWZ(base + p); zr[p] = re[ix]; zi[p] = im[ix]; }
    idft8(zr, zi);
#pragma unroll
    for (int m = 0; m < 8; m++) { const int ix = SWZ(base + m); re[ix] = zr[m]; im[ix] = zi[m]; }
  }
  __syncthreads();
  // ---- inverse stage 3': conj twiddle then radix-8, span 8 ----
  {
    const int base = ((tid >> 3) << 6) | (tid & 7);
#pragma unroll
    for (int p = 0; p < 8; p++) { const int ix = SWZ(base + (p << 3)); zr[p] = re[ix]; zi[p] = im[ix]; }
    twmul7(zr, zi, c8, -s8);
    idft8(zr, zi);
#pragma unroll
    for (int m = 0; m < 8; m++) { const int ix = SWZ(base + (m << 3)); re[ix] = zr[m]; im[ix] = zi[m]; }
  }
  __syncthreads();
  // ---- inverse stage 2': conj twiddle then radix-8, span 64 ----
  {
    const int base = ((tid >> 6) << 9) | (tid & 63);
#pragma unroll
    for (int p = 0; p < 8; p++) { const int ix = SWZ(base + (p << 6)); zr[p] = re[ix]; zi[p] = im[ix]; }
    twmul7(zr, zi, c64, -s64);
    idft8(zr, zi);
#pragma unroll
    for (int m = 0; m < 8; m++) { const int ix = SWZ(base + (m << 6)); re[ix] = zr[m]; im[ix] = zi[m]; }
  }
  __syncthreads();
  // ---- inverse stage 1': conj twiddle + radix-4, span 512; write real/2048 ----
#pragma unroll
  for (int jj = 0; jj < 2; jj++) {
    const int j = tid + (jj << 8);
    const float x0r = re[SWZ(j)];
    const float x1r = re[SWZ(j + 512)],  x1i = im[SWZ(j + 512)];
    const float x2r = re[SWZ(j + 1024)], x2i = im[SWZ(j + 1024)];
    const float x3r = re[SWZ(j + 1536)], x3i = im[SWZ(j + 1536)];
    const float c1 = w1c[jj], s1 = w1s[jj];
    const float c2 = w2c[jj], s2 = w2s[jj];
    const float c3 = w3c[jj], s3 = w3s[jj];
    const float z1r = x1r * c1 + x1i * s1, z1i = x1i * c1 - x1r * s1;
    const float z2r = x2r * c2 + x2i * s2;
    const float z3r = x3r * c3 + x3i * s3, z3i = x3i * c3 - x3r * s3;
    const float ar = x0r + z2r;
    const float br = x0r - z2r;
    const float cr = z1r + z3r;
    const float di = z1i - z3i;
    q[j]        = (ar + cr) * (1.0f / 2048.0f);
    q[j + 512]  = (br - di) * (1.0f / 2048.0f);
    q[j + 1024] = (ar - cr) * (1.0f / 2048.0f);
    q[j + 1536] = (br + di) * (1.0f / 2048.0f);
  }
}

// ---------- fused transpose + hamilton + sp_ln + gate + rot + residual + out_ln + quant ----
// VECTORIZED ownership: thread owns d = c2*256 + lane*4 + e (e=0..3).
__global__ __launch_bounds__(256) void fused2q_k(const float* __restrict__ inter,  // (CHB, D, T)
                                                 const float* __restrict__ Hb,     // (chm, D)
                                                 const float* __restrict__ spw, const float* __restrict__ spb,
                                                 const float* __restrict__ gate, const float* __restrict__ rot,
                                                 const float* __restrict__ ow, const float* __restrict__ ob,
                                                 I8* __restrict__ xh8, I8* __restrict__ xl8,
                                                 float* __restrict__ sxc) {
  __shared__ float ti[8 * 1028];   // 8 rows, +4 pad per row (4112B stride, 16B aligned)
  const int tid = threadIdx.x;
  const int m0 = blockIdx.x * 8;
  const int lb = m0 >> 11;
  const int t0 = m0 & (T_ - 1);
  // ---- stage 8t x 1024n tile: float4 along t ----
  {
    const int tq = (tid & 1) * 4;
    const int nb = tid >> 1;
#pragma unroll
    for (int p = 0; p < 8; p++) {
      const int n = p * 128 + nb;
      const float4 v = *(const float4*)(inter + ((size_t)((lb << 10) | n)) * T_ + t0 + tq);
      ti[(tq + 0) * 1028 + n] = fixf(v.x);
      ti[(tq + 1) * 1028 + n] = fixf(v.y);
      ti[(tq + 2) * 1028 + n] = fixf(v.z);
      ti[(tq + 3) * 1028 + n] = fixf(v.w);
    }
  }
  __syncthreads();
  const int wv = tid >> 6, lane = tid & 63;
  float rr_[16];
#pragma unroll
  for (int i = 0; i < 16; i++) rr_[i] = rot[i];
  const int dl = lane * 4;
  const f32x4 g4 = *(const f32x4*)(gate + dl);
#pragma unroll
  for (int rwi = 0; rwi < 2; rwi++) {
    const int tt = wv * 2 + rwi;
    const int m = m0 + tt;
    const size_t mb = (size_t)m * D_;
    const float sxold = sxc[m];
    f32x4 iv[4], hv[4];
#pragma unroll
    for (int c2 = 0; c2 < 4; c2++) {
      iv[c2] = *(const f32x4*)(ti + tt * 1028 + c2 * 256 + dl);
      f32x4 h = *(const f32x4*)(Hb + mb + c2 * 256 + dl);
#pragma unroll
      for (int e = 0; e < 4; e++) h[e] = fixf(h[e]);
      hv[c2] = h;
    }
    f32x4 o[4];
    o[0] = iv[0] * hv[0] - iv[1] * hv[1] - iv[2] * hv[2] - iv[3] * hv[3];
    o[1] = iv[0] * hv[1] + iv[1] * hv[0] + iv[2] * hv[3] - iv[3] * hv[2];
    o[2] = iv[0] * hv[2] - iv[1] * hv[3] + iv[2] * hv[0] + iv[3] * hv[1];
    o[3] = iv[0] * hv[3] + iv[1] * hv[2] - iv[2] * hv[1] + iv[3] * hv[0];
    float s = 0.f, ss = 0.f;
#pragma unroll
    for (int c2 = 0; c2 < 4; c2++)
#pragma unroll
      for (int e = 0; e < 4; e++) { const float x = o[c2][e]; s += x; ss += x * x; }
#pragma unroll
    for (int off = 32; off > 0; off >>= 1) { s += __shfl_xor(s, off); ss += __shfl_xor(ss, off); }
    const float mean = s * (1.0f / 1024.0f);
    const float rstd = rsqrtf(ss * (1.0f / 1024.0f) - mean * mean + 1e-5f);
    f32x4 xf[4];
#pragma unroll
    for (int c2 = 0; c2 < 4; c2++) {
      const f32x4 w4 = *(const f32x4*)(spw + c2 * 256 + dl);
      const f32x4 b4 = *(const f32x4*)(spb + c2 * 256 + dl);
      xf[c2] = ((o[c2] - mean) * rstd * w4 + b4) * g4;
    }
    f32x4 y[4];
#pragma unroll
    for (int j = 0; j < 4; j++) {
      f32x4 a = rr_[j * 4 + 0] * xf[0] + rr_[j * 4 + 1] * xf[1]
              + rr_[j * 4 + 2] * xf[2] + rr_[j * 4 + 3] * xf[3];
      const char4 h4 = *(const char4*)(xh8 + mb + j * 256 + dl);
      const char4 l4 = *(const char4*)(xl8 + mb + j * 256 + dl);
      f32x4 res;
      res[0] = sxold * ((float)h4.x + (float)l4.x * (1.f / 256.f));
      res[1] = sxold * ((float)h4.y + (float)l4.y * (1.f / 256.f));
      res[2] = sxold * ((float)h4.z + (float)l4.z * (1.f / 256.f));
      res[3] = sxold * ((float)h4.w + (float)l4.w * (1.f / 256.f));
      y[j] = a + res;
    }
    float s2 = 0.f, ss2 = 0.f;
#pragma unroll
    for (int j = 0; j < 4; j++)
#pragma unroll
      for (int e = 0; e < 4; e++) { const float x = y[j][e]; s2 += x; ss2 += x * x; }
#pragma unroll
    for (int off = 32; off > 0; off >>= 1) { s2 += __shfl_xor(s2, off); ss2 += __shfl_xor(ss2, off); }
    const float mean2 = s2 * (1.0f / 1024.0f);
    const float rstd2 = rsqrtf(ss2 * (1.0f / 1024.0f) - mean2 * mean2 + 1e-5f);
    f32x4 vout[4];
    float mx = 0.f;
#pragma unroll
    for (int j = 0; j < 4; j++) {
      const f32x4 w4 = *(const f32x4*)(ow + j * 256 + dl);
      const f32x4 b4 = *(const f32x4*)(ob + j * 256 + dl);
      const f32x4 v = (y[j] - mean2) * rstd2 * w4 + b4;
      vout[j] = v;
#pragma unroll
      for (int e = 0; e < 4; e++) mx = fmaxf(mx, fabsf(v[e]));
    }
#pragma unroll
    for (int off = 32; off > 0; off >>= 1) mx = fmaxf(mx, __shfl_xor(mx, off));
    const float mxg = fmaxf(mx, 1e-30f);
    const float sxn = mxg * (1.f / 127.f);
    const float inv = 127.f / mxg;
    if (lane == 0) sxc[m] = sxn;
#pragma unroll
    for (int j = 0; j < 4; j++) {
      char4 ho, lo2;
      int qh, ql;
      quant2(vout[j][0], inv, qh, ql); ho.x = (I8)qh; lo2.x = (I8)ql;
      quant2(vout[j][1], inv, qh, ql); ho.y = (I8)qh; lo2.y = (I8)ql;
      quant2(vout[j][2], inv, qh, ql); ho.z = (I8)qh; lo2.z = (I8)ql;
      quant2(vout[j][3], inv, qh, ql); ho.w = (I8)qh; lo2.w = (I8)ql;
      *(char4*)(xh8 + mb + j * 256 + dl) = ho;
      *(char4*)(xl8 + mb + j * 256 + dl) = lo2;
    }
  }
}

// ---------- mean over T (partials + atomics; pooled must be zeroed) ----------
__global__ __launch_bounds__(256) void poolq_k(const I8* __restrict__ xh, const I8* __restrict__ xl,
                                               const float* __restrict__ sx,
                                               float* __restrict__ pooled) {
  const int b = blockIdx.z;
  const int d = blockIdx.x * 256 + threadIdx.x;
  const int t0 = blockIdx.y * 256;
  float s = 0.f;
  for (int t = t0; t < t0 + 256; t++) {
    const int row = b * T_ + t;
    const size_t idx = (size_t)row * D_ + d;
    s += sx[row] * ((float)xh[idx] + (float)xl[idx] * (1.f / 256.f));
  }
  atomicAdd(&pooled[b * D_ + d], s);
}

// ---------- classifier LN ----------
__global__ __launch_bounds__(256) void clsln_k(const float* __restrict__ pooled, const float* __restrict__ w,
                                               const float* __restrict__ bias, float* __restrict__ h) {
  __shared__ float red[8];
  const int b = blockIdx.x;
  const int d = threadIdx.x;
  float v[4];
#pragma unroll
  for (int j = 0; j < 4; j++) v[j] = fixf(pooled[b * D_ + j * 256 + d]) * (1.0f / (float)T_);
  float s = v[0] + v[1] + v[2] + v[3];
  float ss = v[0] * v[0] + v[1] * v[1] + v[2] * v[2] + v[3] * v[3];
  breduce2(s, ss, red);
  const float mean = s * (1.0f / (float)D_);
  const float rstd = rsqrtf(ss * (1.0f / (float)D_) - mean * mean + 1e-5f);
#pragma unroll
  for (int j = 0; j < 4; j++)
    h[b * D_ + j * 256 + d] = (v[j] - mean) * rstd * w[j * 256 + d] + bias[j * 256 + d];
}

// ---------- classifier GEMM: one wave per (b, n) ----------
__global__ __launch_bounds__(256) void cls_k(const float* __restrict__ h, const float* __restrict__ W,
                                             const float* __restrict__ cb, float* __restrict__ out) {
  const int wv = blockIdx.x * 4 + (threadIdx.x >> 6);
  const int lane = threadIdx.x & 63;
  const int b = wv / NCLS_;
  const int n = wv - b * NCLS_;
  const float* hb = h + b * D_;
  const float* wr = W + (size_t)n * D_;
  float s = 0.f;
  for (int j = lane; j < D_; j += 64) s += hb[j] * wr[j];
#pragma unroll
  for (int off = 32; off > 0; off >>= 1) s += __shfl_down(s, off);
  if (lane == 0) out[b * NCLS_ + n] = fixf(s + cb[n]);
}

// ---------- launch ----------
extern "C" void kernel_launch(void* const* d_in, const int* in_sizes, int n_in,
                              void* d_out, int out_size, void* d_ws, size_t ws_size,
                              hipStream_t stream) {
  (void)in_sizes; (void)n_in; (void)out_size;
  const int* tokens = (const int*)d_in[0];
  const float* emb = (const float*)d_in[1];
  const float* pos = (const float*)d_in[2];
  const float* Wq = (const float*)d_in[3];
  const float* bq = (const float*)d_in[4];
  const float* Wr = (const float*)d_in[5];
  const float* br = (const float*)d_in[6];
  const float* Wh = (const float*)d_in[7];
  const float* bh = (const float*)d_in[8];
  const float* alpha = (const float*)d_in[9];
  const float* spw = (const float*)d_in[10];
  const float* spb = (const float*)d_in[11];
  const float* gate = (const float*)d_in[12];
  const float* rot = (const float*)d_in[13];
  const float* outw = (const float*)d_in[14];
  const float* outb = (const float*)d_in[15];
  const float* clw = (const float*)d_in[16];
  const float* clb = (const float*)d_in[17];
  const float* clsW = (const float*)d_in[18];
  const float* clsb = (const float*)d_in[19];
  float* out = (float*)d_out;

  // ---- layout: all-layer weight planes + adaptive chunking ----
  // fixed: xh8 16 + xl8 16 + Wh8 12 + Wl8 12 + scales 1 = 57MB
  // f32 bufs: 3 * CHB * 8MB  (CHB=8: 192 -> 249 total; 4: 153; 2: 105; 1: 81)
  const size_t MB = 1048576;
  int CHB;
  if      (ws_size >= 250 * MB) CHB = 8;
  else if (ws_size >= 154 * MB) CHB = 4;
  else if (ws_size >= 106 * MB) CHB = 2;
  else                          CHB = 1;
  const int nchunks = B_ / CHB;
  const int chm = CHB * T_;
  const size_t chunkf = (size_t)CHB * T_ * D_ * 4;

  char* ws = (char*)d_ws;
  I8* xh8 = (I8*)ws;                       // 16 MB
  I8* xl8 = (I8*)(ws + 16 * MB);           // 16 MB
  I8* Wh8 = (I8*)(ws + 32 * MB);           // 12 MB (L x {Q,R,H})
  I8* Wl8 = (I8*)(ws + 44 * MB);           // 12 MB
  float* sx = (float*)(ws + 56 * MB);      // 64 KB (per-row x scales)
  float* sw = (float*)(ws + 56 * MB + 65536);  // 48 KB (per-row W scales, L*3 mats)
  char* fb = ws + 57 * MB;
  float* QTc = (float*)fb;
  float* RTc = (float*)(fb + chunkf);
  float* Hc  = (float*)(fb + 2 * chunkf);
  float* pooled = (float*)fb;              // reuse after layers
  float* hbuf   = (float*)(fb + 32768);

  embedq_k<<<M_, 256, 0, stream>>>(tokens, emb, pos, xh8, xl8, sx);
  wsplitq_k<<<L_ * 3072, 256, 0, stream>>>(Wq, Wr, Wh, Wh8, Wl8, sw);

  const dim3 gemm_grid(24, chm / 128);
  for (int l = 0; l < L_; l++) {
    const I8* Whl = Wh8 + (size_t)l * 3 * DD_;
    const I8* Wll = Wl8 + (size_t)l * 3 * DD_;
    const float* swl = sw + (size_t)l * 3 * D_;
    for (int c = 0; c < nchunks; c++) {
      const size_t xoff = (size_t)c * chm * D_;
      gemm3q_k<<<gemm_grid, 256, 0, stream>>>(xh8 + xoff, xl8 + xoff, Whl, Wll,
                                              sx + (size_t)c * chm, swl,
                                              bq + l * D_, br + l * D_, bh + l * D_,
                                              QTc, RTc, Hc);
      fft_spectral_k<<<CHB * D_, 256, 0, stream>>>(QTc, RTc, alpha + l * QD_);
      fused2q_k<<<chm / 8, 256, 0, stream>>>(QTc, Hc, spw + l * D_, spb + l * D_,
                                             gate + l * QD_, rot + l * 16,
                                             outw + l * D_, outb + l * D_,
                                             xh8 + xoff, xl8 + xoff, sx + (size_t)c * chm);
    }
  }

  hipMemsetAsync(pooled, 0, B_ * D_ * sizeof(float), stream);
  poolq_k<<<dim3(4, 8, 8), 256, 0, stream>>>(xh8, xl8, sx, pooled);
  clsln_k<<<B_, 256, 0, stream>>>(pooled, clw, clb, hbuf);
  cls_k<<<(B_ * NCLS_) / 4, 256, 0, stream>>>(hbuf, clsW, clsb, out);
}